// Round 3
// baseline (1485.408 us; speedup 1.0000x reference)
//
#include <hip/hip_runtime.h>
#include <hip/hip_bf16.h>

// Problem constants
#define B_    16
#define T_    1000
#define FEAT  771
#define FEATP 800      // 771 padded to 25*32 (exact BK multiple -> guard-free GEMM)
#define H_    512
#define H3    1536
#define KN_   9
#define KHID  4608     // H*KN
#define M_    16000    // B*T
#define NOUT  257      // output column slice [257:514)
#define KSLICES 3      // split-K factor for the final GEMM

typedef _Float16 half8 __attribute__((ext_vector_type(8)));
typedef _Float16 half4 __attribute__((ext_vector_type(4)));
typedef _Float16 half2v __attribute__((ext_vector_type(2)));
typedef _Float16 h2 __attribute__((ext_vector_type(2)));
typedef float    floatx4 __attribute__((ext_vector_type(4)));

// tanh(z) = 1 - 2/(1+e^{2z})  — saturates correctly at +/-inf, no NaN
__device__ inline float tanh_fast(float z) {
    return 1.0f - 2.0f / (1.0f + __expf(2.0f * z));
}
__device__ inline float sigmoid_fast(float z) {
    return 1.0f / (1.0f + __expf(-z));
}

// async global->LDS, 16B per lane; LDS dst must be wave-uniform base
__device__ inline void gload16(const _Float16* g, _Float16* l) {
    __builtin_amdgcn_global_load_lds(
        (const __attribute__((address_space(1))) void*)g,
        (__attribute__((address_space(3))) void*)l, 16, 0, 0);
}

// packed fp16 fma: d = a*b + c  (v_pk_fma_f16)
__device__ inline h2 pkfma(unsigned int w, unsigned int x, h2 c) {
    const h2 a = __builtin_bit_cast(h2, w);
    const h2 b = __builtin_bit_cast(h2, x);
#if __has_builtin(__builtin_elementwise_fma)
    return __builtin_elementwise_fma(a, b, c);
#else
    return a * b + c;
#endif
}

// ---------------------------------------------------------------------------
// fp32 -> fp16 convert of inputs, padding rows 771 -> 800 with zeros
__global__ void convert_inputs(const float* __restrict__ in, _Float16* __restrict__ A1) {
    size_t i = (size_t)blockIdx.x * 256 + threadIdx.x;
    if (i >= (size_t)M_ * FEATP) return;
    size_t r = i / FEATP;
    int   cc = (int)(i % FEATP);
    A1[i] = (cc < FEAT) ? (_Float16)in[r * FEAT + cc] : (_Float16)0.f;
}

// ---------------------------------------------------------------------------
// Pack conv weights into dup'd half2 u32: ckp[i] = (h(ck[i]), h(ck[i]))
__global__ void pack_ck(const float* __restrict__ ck, unsigned int* __restrict__ ckp) {
    const int i = threadIdx.x;
    if (i < 9 * 36) {
        const _Float16 w = (_Float16)ck[i];
        const unsigned short u = __builtin_bit_cast(unsigned short, w);
        ckp[i] = ((unsigned int)u << 16) | u;
    }
}

// ---------------------------------------------------------------------------
// LDS-tiled transpose+convert: Wt[n*Kp + kidx] = (k<K) ? W[k*ldw + coloff + n] : 0
// perm9: kidx = (k%9)*512 + k/9  (k-major planes for the conv output layout)
__global__ __launch_bounds__(256) void transpose_w(
    const float* __restrict__ W, _Float16* __restrict__ Wt,
    int K, int N, int ldw, int coloff, int Kp, int perm9)
{
    __shared__ float tile[32][33];
    const int kb = blockIdx.x * 32;
    const int nb = blockIdx.y * 32;
    const int tx = threadIdx.x & 31;
    const int ty = threadIdx.x >> 5;   // 0..7
    #pragma unroll
    for (int r = ty; r < 32; r += 8) {
        const int k = kb + r, n = nb + tx;
        tile[r][tx] = (k < K && n < N) ? W[(size_t)k * ldw + coloff + n] : 0.f;
    }
    __syncthreads();
    #pragma unroll
    for (int r = ty; r < 32; r += 8) {
        const int n = nb + r, k = kb + tx;
        if (n < N && k < Kp) {
            size_t kidx = (size_t)k;
            if (perm9) kidx = (size_t)(k % 9) * 512 + (size_t)(k / 9);
            Wt[(size_t)n * Kp + kidx] = (_Float16)tile[tx][r];
        }
    }
}

// ---------------------------------------------------------------------------
// Tiled fp16 MFMA GEMM: C[M x N] = A[M x Kp] * Bt[N x Kp]^T, fp32 accumulate.
// 128x128 block tile, BK=32, 4 waves (2x2), each wave 4x4 of 16x16x32 MFMA.
// Staging via global_load_lds width=16 (async, guard-free).
template <int EPI>
__global__ __launch_bounds__(256) void gemm_kernel(
    const _Float16* __restrict__ A, const _Float16* __restrict__ Bt,
    int Kp, int nk, int Nb,
    _Float16* __restrict__ Ch, float* __restrict__ Cf, int ldc,
    const float* __restrict__ bias)
{
    __shared__ __align__(16) _Float16 As[128][32];   // linear, global_load_lds dest
    __shared__ __align__(16) _Float16 Bs[128][32];

    const int tid  = threadIdx.x;
    const int m0   = blockIdx.x * 128;
    const int n0   = blockIdx.y * 128;
    const int koff = blockIdx.z * (nk << 5);   // K-slice origin
    const int wave = tid >> 6;
    const int lane = tid & 63;
    const int wr   = (wave >> 1) << 6;   // wave row offset (0/64)
    const int wc   = (wave & 1) << 6;    // wave col offset (0/64)
    const int lrow = lane & 15;
    const int lq   = lane >> 4;          // 0..3

    // staging: wave w stages rows [w*32, w*32+32), 2 instrs per matrix
    const int srow0  = wave * 32 + (lane >> 2);   // rows for instr 0
    const int schunk = (lane & 3) * 8;            // halves within row
    const _Float16* aSrc = A  + (size_t)(m0 + srow0) * Kp + koff + schunk;
    const _Float16* bSrc = Bt + (size_t)(n0 + srow0) * Kp + koff + schunk;
    _Float16* aDst0 = &As[wave * 32][0];
    _Float16* aDst1 = &As[wave * 32 + 16][0];
    _Float16* bDst0 = &Bs[wave * 32][0];
    _Float16* bDst1 = &Bs[wave * 32 + 16][0];
    const size_t rstep = (size_t)16 * Kp;

    floatx4 acc[4][4];
    #pragma unroll
    for (int i = 0; i < 4; ++i)
        #pragma unroll
        for (int j = 0; j < 4; ++j)
            #pragma unroll
            for (int r = 0; r < 4; ++r) acc[i][j][r] = 0.f;

    for (int kc = 0; kc < nk; ++kc) {
        __syncthreads();                 // previous iter's frag reads done
        gload16(aSrc,         aDst0);
        gload16(aSrc + rstep, aDst1);
        gload16(bSrc,         bDst0);
        gload16(bSrc + rstep, bDst1);
        aSrc += 32; bSrc += 32;
        __syncthreads();                 // drains vmcnt -> LDS tile ready

        half8 af[4], bfr[4];
        #pragma unroll
        for (int i = 0; i < 4; ++i) af[i]  = *(const half8*)(&As[wr + i * 16 + lrow][lq * 8]);
        #pragma unroll
        for (int j = 0; j < 4; ++j) bfr[j] = *(const half8*)(&Bs[wc + j * 16 + lrow][lq * 8]);
        #pragma unroll
        for (int i = 0; i < 4; ++i)
            #pragma unroll
            for (int j = 0; j < 4; ++j)
                acc[i][j] = __builtin_amdgcn_mfma_f32_16x16x32_f16(af[i], bfr[j], acc[i][j], 0, 0, 0);
    }

    // Epilogue: C/D layout col=lane&15, row=quad*4+reg
    #pragma unroll
    for (int j = 0; j < 4; ++j) {
        const int col = n0 + wc + j * 16 + lrow;
        if (col >= Nb) continue;
        #pragma unroll
        for (int i = 0; i < 4; ++i) {
            #pragma unroll
            for (int r = 0; r < 4; ++r) {
                const int row = m0 + wr + i * 16 + lq * 4 + r;
                float v = acc[i][j][r];
                if constexpr (EPI == 0) {
                    float z = v + bias[col];
                    Ch[(size_t)row * ldc + col] = (_Float16)tanh_fast(z);
                } else if constexpr (EPI == 1) {
                    Ch[(size_t)(col >> 9) * ((size_t)M_ * 512) + (size_t)row * 512 + (col & 511)] = (_Float16)v;
                } else {
                    Cf[(size_t)blockIdx.z * M_ * NOUT + (size_t)row * NOUT + col] = v;
                }
            }
        }
    }
}

// ---------------------------------------------------------------------------
// Split-K reduction + sigmoid epilogue for the final GEMM.
__global__ __launch_bounds__(256) void reduce_out(
    const float* __restrict__ Cp, const float* __restrict__ bias,
    const float* __restrict__ aux, float* __restrict__ out)
{
    const size_t i = (size_t)blockIdx.x * 256 + threadIdx.x;
    if (i >= (size_t)M_ * NOUT) return;
    const int row = (int)(i / NOUT);
    const int col = (int)(i % NOUT);
    float s = Cp[i] + Cp[i + (size_t)M_ * NOUT] + Cp[i + 2 * (size_t)M_ * NOUT];
    out[i] = sigmoid_fast(s + bias[col]) * aux[(size_t)row * FEAT + 257 + col];
}

// ---------------------------------------------------------------------------
// SRU scan reading the SoA U planes + X directly (repack kernel eliminated).
// One lane per h: all four streams are perfectly coalesced (64 consecutive
// ushorts per wave). ushort loads = full-register zero-extend -> no d16
// partial-write merge deps. Depth-20 register ring per stream.
__global__ __launch_bounds__(64) void sru_scan(
    const _Float16* __restrict__ U,   // 3 planes [M][512] (xt, fp, rp)
    const _Float16* __restrict__ X,   // [M][512] layer input
    _Float16* __restrict__ Xout,
    const float* __restrict__ v, const float* __restrict__ bg)
{
    const int gid = blockIdx.x * 64 + threadIdx.x;
    const int b = gid >> 9;
    const int h = gid & 511;
    const float vf = v[h],      vr = v[512 + h];
    const float bf = bg[h],     br = bg[512 + h];

    const unsigned short* pa = (const unsigned short*)U + (size_t)b * T_ * 512 + h;
    const unsigned short* pf = pa + (size_t)M_ * 512;
    const unsigned short* pr = pa + 2 * (size_t)M_ * 512;
    const unsigned short* px = (const unsigned short*)X + (size_t)b * T_ * 512 + h;
    _Float16* ox = Xout + (size_t)b * T_ * 512 + h;

    unsigned short ba[20], bb[20], bc[20], bd[20];
    #pragma unroll
    for (int j = 0; j < 20; ++j) {
        ba[j] = pa[(size_t)j * 512];
        bb[j] = pf[(size_t)j * 512];
        bc[j] = pr[(size_t)j * 512];
        bd[j] = px[(size_t)j * 512];
    }

    float c = 0.f;
    for (int t0 = 0; t0 < T_; t0 += 20) {
        #pragma unroll
        for (int j = 0; j < 20; ++j) {
            const int t = t0 + j;
            const float xt = (float)__builtin_bit_cast(_Float16, ba[j]);
            const float fp = (float)__builtin_bit_cast(_Float16, bb[j]);
            const float rp = (float)__builtin_bit_cast(_Float16, bc[j]);
            const float x  = (float)__builtin_bit_cast(_Float16, bd[j]);
            const int tn = t + 20;
            if (tn < T_) {
                ba[j] = pa[(size_t)tn * 512];
                bb[j] = pf[(size_t)tn * 512];
                bc[j] = pr[(size_t)tn * 512];
                bd[j] = px[(size_t)tn * 512];
            }
            const float f  = sigmoid_fast(fp + vf * c + bf);
            const float r  = sigmoid_fast(rp + vr * c + br);
            const float cn = f * c + (1.0f - f) * xt;
            const float hO = r * cn + (1.0f - r) * x;
            ox[(size_t)t * 512] = (_Float16)hO;
            c = cn;
        }
    }
}

// ---------------------------------------------------------------------------
// Fused conv6x6(asym pad 3,2) + maxpool3x3(pad 1) + bias + tanh.
// Conv math in packed fp16 (v_pk_fma_f16): in_s kept fp16 (8-B lane stride ->
// 4-way LDS conflict instead of 8-way), 648 pk_fma + 24 alignbit per thread
// replaces 1296 v_fma_f32, raw fp16 accs stored to cv without cvt.
// tanh AFTER pool (monotonic). Output layout k-major (k*512+h).
#define CVW 76   // cv row width (halves)

__global__ __launch_bounds__(320) void conv_pool(
    const _Float16* __restrict__ X, const unsigned int* __restrict__ ckp,
    const float* __restrict__ cb, _Float16* __restrict__ A3)
{
    __shared__ __align__(16) _Float16 in_s[23][80];       // fp16, rows padded to 80
    __shared__ __align__(16) _Float16 cv[9][18][CVW];     // raw conv fp16; -65504 = outside
    const int tid = threadIdx.x;
    int bi = blockIdx.x;
    const int th = bi & 7;  bi >>= 3;
    const int tt = bi % 63;
    const int b  = bi / 63;
    const int t0 = tt * 16, h0 = th * 64;

    for (int i = tid; i < 23 * 76; i += 320) {
        const int r = i / 76, cc = i % 76;
        const int gt = t0 - 4 + r, gh = h0 - 4 + cc;
        _Float16 val = (_Float16)0.f;   // conv zero-padding
        if (gt >= 0 && gt < T_ && gh >= 0 && gh < H_)
            val = X[((size_t)b * T_ + gt) * H_ + gh];
        in_s[r][cc] = val;
    }
    __syncthreads();

    // conv phase: 18 pt x 17 ph-groups = 306 tasks, one per thread
    if (tid < 306) {
        const int pt = tid / 17;        // conv row: ct = t0 - 1 + pt
        const int co = (tid % 17) * 4;  // conv col offset (co % 4 == 0)

        const int ct = t0 - 1 + pt;
        const bool rok = (ct >= 0) && (ct < T_);
        const int chb = h0 - 1 + co;
        const bool ok0 = rok && (chb + 0 >= 0) && (chb + 0 < H_);
        const bool ok1 = rok && (chb + 1 >= 0) && (chb + 1 < H_);
        const bool ok2 = rok && (chb + 2 >= 0) && (chb + 2 < H_);
        const bool ok3 = rok && (chb + 3 >= 0) && (chb + 3 < H_);

        h2 acc0[9], acc1[9];            // (q0,q1) and (q2,q3) accumulators
        #pragma unroll
        for (int k = 0; k < 9; ++k) {
            acc0[k][0] = (_Float16)0.f; acc0[k][1] = (_Float16)0.f;
            acc1[k][0] = (_Float16)0.f; acc1[k][1] = (_Float16)0.f;
        }

        #pragma unroll 1
        for (int ii = 0; ii < 6; ++ii) {
            const unsigned int* rw = (const unsigned int*)&in_s[pt + ii][co];  // 8-B aligned
            const uint2 a01 = *(const uint2*)(rw);
            const uint2 a23 = *(const uint2*)(rw + 2);
            const unsigned int A0 = a01.x, A1v = a01.y, A2 = a23.x, A3v = a23.y;
            const unsigned int A4 = rw[4];
            // misaligned pairs: Mm[i] = halves(co+2i+1, co+2i+2)
            const unsigned int M0 = (A0  >> 16) | (A1v << 16);
            const unsigned int M1 = (A1v >> 16) | (A2  << 16);
            const unsigned int M2 = (A2  >> 16) | (A3v << 16);
            const unsigned int M3 = (A3v >> 16) | (A4  << 16);

            const unsigned int* wt = ckp + ii * 6;   // + k*36 + J, wave-uniform
            #pragma unroll
            for (int k = 0; k < 9; ++k) {
                const unsigned int* wk = wt + k * 36;
                acc0[k] = pkfma(wk[0], A0,  acc0[k]);  acc1[k] = pkfma(wk[0], A1v, acc1[k]); // J=0
                acc0[k] = pkfma(wk[1], M0,  acc0[k]);  acc1[k] = pkfma(wk[1], M1,  acc1[k]); // J=1
                acc0[k] = pkfma(wk[2], A1v, acc0[k]);  acc1[k] = pkfma(wk[2], A2,  acc1[k]); // J=2
                acc0[k] = pkfma(wk[3], M1,  acc0[k]);  acc1[k] = pkfma(wk[3], M2,  acc1[k]); // J=3
                acc0[k] = pkfma(wk[4], A2,  acc0[k]);  acc1[k] = pkfma(wk[4], A3v, acc1[k]); // J=4
                acc0[k] = pkfma(wk[5], M2,  acc0[k]);  acc1[k] = pkfma(wk[5], M3,  acc1[k]); // J=5
            }
        }

        const _Float16 NEG = (_Float16)(-65504.f);
        #pragma unroll
        for (int k = 0; k < 9; ++k) {
            half4 o;
            o[0] = ok0 ? acc0[k][0] : NEG;
            o[1] = ok1 ? acc0[k][1] : NEG;
            o[2] = ok2 ? acc1[k][0] : NEG;
            o[3] = ok3 ? acc1[k][1] : NEG;
            *(half4*)(&cv[k][pt][co]) = o;
        }
    }
    __syncthreads();

    // pool phase: 16 pt x 16 ph-groups of 4 = 256 tasks; bias+tanh here
    if (tid < 256) {
        const int pt = tid >> 4;
        const int gt = t0 + pt;
        if (gt < T_) {
            const int ph = (tid & 15) * 4;
            _Float16* dst = A3 + ((size_t)b * T_ + gt) * KHID + (h0 + ph);
            #pragma unroll
            for (int k = 0; k < 9; ++k) {
                float q0 = -1e30f, q1 = -1e30f, q2 = -1e30f, q3 = -1e30f;
                #pragma unroll
                for (int dr = 0; dr < 3; ++dr) {
                    const _Float16* cr = &cv[k][pt + dr][ph];
                    const half4  a = *(const half4*)(cr);
                    const half2v bq = *(const half2v*)(cr + 4);
                    const float v0 = (float)a[0], v1 = (float)a[1], v2 = (float)a[2];
                    const float v3 = (float)a[3], v4 = (float)bq[0], v5 = (float)bq[1];
                    const float t01 = fmaxf(v1, v2);
                    const float t34 = fmaxf(v3, v4);
                    q0 = fmaxf(q0, fmaxf(v0, t01));
                    q1 = fmaxf(q1, fmaxf(t01, v3));
                    q2 = fmaxf(q2, fmaxf(v2, t34));
                    q3 = fmaxf(q3, fmaxf(t34, v5));
                }
                const float bk = cb[k];
                half4 o;
                o[0] = (_Float16)tanh_fast(q0 + bk);
                o[1] = (_Float16)tanh_fast(q1 + bk);
                o[2] = (_Float16)tanh_fast(q2 + bk);
                o[3] = (_Float16)tanh_fast(q3 + bk);
                *(half4*)(dst + (size_t)k * 512) = o;
            }
        }
    }
}

// ---------------------------------------------------------------------------
extern "C" void kernel_launch(void* const* d_in, const int* in_sizes, int n_in,
                              void* d_out, int out_size, void* d_ws, size_t ws_size,
                              hipStream_t stream) {
    const float* inputs = (const float*)d_in[0];
    const float* W_in   = (const float*)d_in[1];
    const float* b_in   = (const float*)d_in[2];
    const float* W_rnn  = (const float*)d_in[3];
    const float* v_rnn  = (const float*)d_in[4];
    const float* b_rnn  = (const float*)d_in[5];
    const float* conv_k = (const float*)d_in[6];
    const float* conv_b = (const float*)d_in[7];
    const float* W_out  = (const float*)d_in[8];
    const float* b_out  = (const float*)d_in[9];
    float* out = (float*)d_out;

    char* ws = (char*)d_ws;
    size_t off = 0;
    auto take = [&](size_t bytes) -> char* {
        off = (off + 255) & ~(size_t)255;
        char* p = ws + off;
        off += bytes;
        return p;
    };
    // W3T first so it survives; A1..X1 form a dead span at G3 time for Cp alias.
    _Float16* W3T  = (_Float16*)take((size_t)NOUT * KHID * 2);  // W_out[:,257:514)^T, K-permuted
    _Float16* A1   = (_Float16*)take((size_t)M_ * FEATP * 2);   // inputs fp16, padded (dead after G1)
    _Float16* W1T  = (_Float16*)take((size_t)H_ * FEATP * 2);   // W_in^T
    _Float16* W2T0 = (_Float16*)take((size_t)H3 * H_ * 2);      // W_rnn[0]^T
    _Float16* W2T1 = (_Float16*)take((size_t)H3 * H_ * 2);      // W_rnn[1]^T
    _Float16* X0   = (_Float16*)take((size_t)M_ * H_ * 2);      // tanh(G1); scan1 output (X2)
    _Float16* X1   = (_Float16*)take((size_t)M_ * H_ * 2);      // scan0 output
    _Float16* U    = (_Float16*)take(3 * (size_t)M_ * 512 * 2); // SoA U planes (xt,fp,rp)
    _Float16* A3   = (_Float16*)take((size_t)M_ * KHID * 2);    // pooled conv, k-major (k*512+h)
    unsigned int* ckp = (unsigned int*)take(9 * 36 * 4);        // packed dup'd fp16 conv weights
    // Split-K partials alias the dead A1..X1 span (49.4 MB < 62.4 MB span):
    float* Cp = (float*)A1;
    _Float16* X2 = X0;  // X0 dead after G2-layer0 feed -> reuse for scan1 output

    // --- weight/input preprocessing (fp32 -> fp16, transpose to NxK) ---
    {
        size_t n = (size_t)M_ * FEATP;
        convert_inputs<<<dim3((unsigned)((n + 255) / 256)), 256, 0, stream>>>(inputs, A1);
    }
    pack_ck<<<dim3(1), 384, 0, stream>>>(conv_k, ckp);
    transpose_w<<<dim3(25, 16), 256, 0, stream>>>(W_in, W1T, FEAT, H_, H_, 0, FEATP, 0);
    transpose_w<<<dim3(16, 48), 256, 0, stream>>>(W_rnn, W2T0, H_, H3, H3, 0, H_, 0);
    transpose_w<<<dim3(16, 48), 256, 0, stream>>>(W_rnn + (size_t)H_ * H3, W2T1, H_, H3, H3, 0, H_, 0);
    transpose_w<<<dim3(144, 9), 256, 0, stream>>>(W_out, W3T, KHID, NOUT, FEAT, 257, KHID, 1);

    // --- G1: X0 = tanh(inputs @ W_in + b_in) ---
    gemm_kernel<0><<<dim3(125, 4), 256, 0, stream>>>(A1, W1T, FEATP, 25, H_, X0, nullptr, H_, b_in);

    // --- SRU layer 0: U-GEMM (SoA) -> scan (reads planes directly) ---
    gemm_kernel<1><<<dim3(125, 12), 256, 0, stream>>>(X0, W2T0, H_, 16, H3, U, nullptr, 0, nullptr);
    sru_scan<<<dim3(128), 64, 0, stream>>>(U, X0, X1, v_rnn, b_rnn);

    // --- SRU layer 1 ---
    gemm_kernel<1><<<dim3(125, 12), 256, 0, stream>>>(X1, W2T1, H_, 16, H3, U, nullptr, 0, nullptr);
    sru_scan<<<dim3(128), 64, 0, stream>>>(U, X1, X2, v_rnn + 1024, b_rnn + 1024);

    // --- conv + maxpool + bias + tanh fused, producing final-GEMM A matrix ---
    conv_pool<<<dim3(16 * 63 * 8), 320, 0, stream>>>(X2, ckp, conv_b, A3);

    // --- G3 split-K: Cp[z] = A3 @ W3T (K-slice z), then reduce+sigmoid+mask ---
    gemm_kernel<3><<<dim3(125, 3, KSLICES), 256, 0, stream>>>(A3, W3T, KHID, 144 / KSLICES, NOUT, nullptr, Cp, 0, nullptr);
    {
        const unsigned nred = (unsigned)(((size_t)M_ * NOUT + 255) / 256);
        reduce_out<<<dim3(nred), 256, 0, stream>>>(Cp, b_out + 257, inputs, out);
    }
}

// Round 4
// 816.202 us; speedup vs baseline: 1.8199x; 1.8199x over previous
//
#include <hip/hip_runtime.h>
#include <hip/hip_bf16.h>

// Problem constants
#define B_    16
#define T_    1000
#define FEAT  771
#define FEATP 800      // 771 padded to 25*32 (exact BK multiple -> guard-free GEMM)
#define H_    512
#define H3    1536
#define KN_   9
#define KHID  4608     // H*KN
#define M_    16000    // B*T
#define NOUT  257      // output column slice [257:514)
#define KSLICES 3      // split-K factor for the final GEMM

typedef _Float16 half8 __attribute__((ext_vector_type(8)));
typedef _Float16 half4 __attribute__((ext_vector_type(4)));
typedef _Float16 half2v __attribute__((ext_vector_type(2)));
typedef _Float16 h2 __attribute__((ext_vector_type(2)));
typedef float    floatx4 __attribute__((ext_vector_type(4)));

// tanh(z) = 1 - 2/(1+e^{2z})  — saturates correctly at +/-inf, no NaN
__device__ inline float tanh_fast(float z) {
    return 1.0f - 2.0f / (1.0f + __expf(2.0f * z));
}
__device__ inline float sigmoid_fast(float z) {
    return 1.0f / (1.0f + __expf(-z));
}

// async global->LDS, 16B per lane; LDS dst must be wave-uniform base
__device__ inline void gload16(const _Float16* g, _Float16* l) {
    __builtin_amdgcn_global_load_lds(
        (const __attribute__((address_space(1))) void*)g,
        (__attribute__((address_space(3))) void*)l, 16, 0, 0);
}

// packed fp16 fma: d = a*b + c  (v_pk_fma_f16)
__device__ inline h2 pkfma(unsigned int w, unsigned int x, h2 c) {
    const h2 a = __builtin_bit_cast(h2, w);
    const h2 b = __builtin_bit_cast(h2, x);
#if __has_builtin(__builtin_elementwise_fma)
    return __builtin_elementwise_fma(a, b, c);
#else
    return a * b + c;
#endif
}

// ---------------------------------------------------------------------------
// fp32 -> fp16 convert of inputs, padding rows 771 -> 800 with zeros
__global__ void convert_inputs(const float* __restrict__ in, _Float16* __restrict__ A1) {
    size_t i = (size_t)blockIdx.x * 256 + threadIdx.x;
    if (i >= (size_t)M_ * FEATP) return;
    size_t r = i / FEATP;
    int   cc = (int)(i % FEATP);
    A1[i] = (cc < FEAT) ? (_Float16)in[r * FEAT + cc] : (_Float16)0.f;
}

// ---------------------------------------------------------------------------
// Pack conv weights into dup'd half2 u32: ckp[i] = (h(ck[i]), h(ck[i]))
__global__ void pack_ck(const float* __restrict__ ck, unsigned int* __restrict__ ckp) {
    const int i = threadIdx.x;
    if (i < 9 * 36) {
        const _Float16 w = (_Float16)ck[i];
        const unsigned short u = __builtin_bit_cast(unsigned short, w);
        ckp[i] = ((unsigned int)u << 16) | u;
    }
}

// ---------------------------------------------------------------------------
// LDS-tiled transpose+convert: Wt[n*Kp + kidx] = (k<K) ? W[k*ldw + coloff + n] : 0
// perm9: kidx = (k%9)*512 + k/9  (k-major planes for the conv output layout)
__global__ __launch_bounds__(256) void transpose_w(
    const float* __restrict__ W, _Float16* __restrict__ Wt,
    int K, int N, int ldw, int coloff, int Kp, int perm9)
{
    __shared__ float tile[32][33];
    const int kb = blockIdx.x * 32;
    const int nb = blockIdx.y * 32;
    const int tx = threadIdx.x & 31;
    const int ty = threadIdx.x >> 5;   // 0..7
    #pragma unroll
    for (int r = ty; r < 32; r += 8) {
        const int k = kb + r, n = nb + tx;
        tile[r][tx] = (k < K && n < N) ? W[(size_t)k * ldw + coloff + n] : 0.f;
    }
    __syncthreads();
    #pragma unroll
    for (int r = ty; r < 32; r += 8) {
        const int n = nb + r, k = kb + tx;
        if (n < N && k < Kp) {
            size_t kidx = (size_t)k;
            if (perm9) kidx = (size_t)(k % 9) * 512 + (size_t)(k / 9);
            Wt[(size_t)n * Kp + kidx] = (_Float16)tile[tx][r];
        }
    }
}

// ---------------------------------------------------------------------------
// Tiled fp16 MFMA GEMM: C[M x N] = A[M x Kp] * Bt[N x Kp]^T, fp32 accumulate.
// 128x128 block tile, BK=32, 4 waves (2x2), each wave 4x4 of 16x16x32 MFMA.
// Staging via global_load_lds width=16 (async, guard-free).
template <int EPI>
__global__ __launch_bounds__(256) void gemm_kernel(
    const _Float16* __restrict__ A, const _Float16* __restrict__ Bt,
    int Kp, int nk, int Nb,
    _Float16* __restrict__ Ch, float* __restrict__ Cf, int ldc,
    const float* __restrict__ bias)
{
    __shared__ __align__(16) _Float16 As[128][32];   // linear, global_load_lds dest
    __shared__ __align__(16) _Float16 Bs[128][32];

    const int tid  = threadIdx.x;
    const int m0   = blockIdx.x * 128;
    const int n0   = blockIdx.y * 128;
    const int koff = blockIdx.z * (nk << 5);   // K-slice origin
    const int wave = tid >> 6;
    const int lane = tid & 63;
    const int wr   = (wave >> 1) << 6;   // wave row offset (0/64)
    const int wc   = (wave & 1) << 6;    // wave col offset (0/64)
    const int lrow = lane & 15;
    const int lq   = lane >> 4;          // 0..3

    // staging: wave w stages rows [w*32, w*32+32), 2 instrs per matrix
    const int srow0  = wave * 32 + (lane >> 2);   // rows for instr 0
    const int schunk = (lane & 3) * 8;            // halves within row
    const _Float16* aSrc = A  + (size_t)(m0 + srow0) * Kp + koff + schunk;
    const _Float16* bSrc = Bt + (size_t)(n0 + srow0) * Kp + koff + schunk;
    _Float16* aDst0 = &As[wave * 32][0];
    _Float16* aDst1 = &As[wave * 32 + 16][0];
    _Float16* bDst0 = &Bs[wave * 32][0];
    _Float16* bDst1 = &Bs[wave * 32 + 16][0];
    const size_t rstep = (size_t)16 * Kp;

    floatx4 acc[4][4];
    #pragma unroll
    for (int i = 0; i < 4; ++i)
        #pragma unroll
        for (int j = 0; j < 4; ++j)
            #pragma unroll
            for (int r = 0; r < 4; ++r) acc[i][j][r] = 0.f;

    for (int kc = 0; kc < nk; ++kc) {
        __syncthreads();                 // previous iter's frag reads done
        gload16(aSrc,         aDst0);
        gload16(aSrc + rstep, aDst1);
        gload16(bSrc,         bDst0);
        gload16(bSrc + rstep, bDst1);
        aSrc += 32; bSrc += 32;
        __syncthreads();                 // drains vmcnt -> LDS tile ready

        half8 af[4], bfr[4];
        #pragma unroll
        for (int i = 0; i < 4; ++i) af[i]  = *(const half8*)(&As[wr + i * 16 + lrow][lq * 8]);
        #pragma unroll
        for (int j = 0; j < 4; ++j) bfr[j] = *(const half8*)(&Bs[wc + j * 16 + lrow][lq * 8]);
        #pragma unroll
        for (int i = 0; i < 4; ++i)
            #pragma unroll
            for (int j = 0; j < 4; ++j)
                acc[i][j] = __builtin_amdgcn_mfma_f32_16x16x32_f16(af[i], bfr[j], acc[i][j], 0, 0, 0);
    }

    // Epilogue: C/D layout col=lane&15, row=quad*4+reg
    #pragma unroll
    for (int j = 0; j < 4; ++j) {
        const int col = n0 + wc + j * 16 + lrow;
        if (col >= Nb) continue;
        #pragma unroll
        for (int i = 0; i < 4; ++i) {
            #pragma unroll
            for (int r = 0; r < 4; ++r) {
                const int row = m0 + wr + i * 16 + lq * 4 + r;
                float v = acc[i][j][r];
                if constexpr (EPI == 0) {
                    float z = v + bias[col];
                    Ch[(size_t)row * ldc + col] = (_Float16)tanh_fast(z);
                } else if constexpr (EPI == 1) {
                    Ch[(size_t)(col >> 9) * ((size_t)M_ * 512) + (size_t)row * 512 + (col & 511)] = (_Float16)v;
                } else {
                    Cf[(size_t)blockIdx.z * M_ * NOUT + (size_t)row * NOUT + col] = v;
                }
            }
        }
    }
}

// ---------------------------------------------------------------------------
// Split-K reduction + sigmoid epilogue for the final GEMM.
__global__ __launch_bounds__(256) void reduce_out(
    const float* __restrict__ Cp, const float* __restrict__ bias,
    const float* __restrict__ aux, float* __restrict__ out)
{
    const size_t i = (size_t)blockIdx.x * 256 + threadIdx.x;
    if (i >= (size_t)M_ * NOUT) return;
    const int row = (int)(i / NOUT);
    const int col = (int)(i % NOUT);
    float s = Cp[i] + Cp[i + (size_t)M_ * NOUT] + Cp[i + 2 * (size_t)M_ * NOUT];
    out[i] = sigmoid_fast(s + bias[col]) * aux[(size_t)row * FEAT + 257 + col];
}

// ---------------------------------------------------------------------------
// Repack SoA U planes + X into packed Upk[m][h][4] = {xt, fp, rp, x} fp16.
// All loads are 8-B dense (half4 per 4 adjacent h), stores 16-B dense.
// This keeps the scan at ONE 8-B load/step (20 outstanding <= vmcnt limit);
// direct 4-stream scan reads collapse the prefetch pipeline (measured r3).
__global__ __launch_bounds__(256) void repack_u(
    const _Float16* __restrict__ U,   // 3 planes [M][512]
    const _Float16* __restrict__ X,   // [M][512] dense layer input
    _Float16* __restrict__ Upk)       // [M][512][4]
{
    const size_t i = (size_t)blockIdx.x * 256 + threadIdx.x;  // over M*128 4-h groups
    if (i >= (size_t)M_ * 128) return;
    const size_t base = i << 2;       // = m*512 + h (h multiple of 4)
    const half4 a = *(const half4*)(U + base);
    const half4 f = *(const half4*)(U + (size_t)M_ * 512 + base);
    const half4 r = *(const half4*)(U + 2 * (size_t)M_ * 512 + base);
    const half4 x = *(const half4*)(X + base);
    half8 lo, hi;
    lo[0] = a[0]; lo[1] = f[0]; lo[2] = r[0]; lo[3] = x[0];
    lo[4] = a[1]; lo[5] = f[1]; lo[6] = r[1]; lo[7] = x[1];
    hi[0] = a[2]; hi[1] = f[2]; hi[2] = r[2]; hi[3] = x[2];
    hi[4] = a[3]; hi[5] = f[3]; hi[6] = r[3]; hi[7] = x[3];
    *(half8*)(Upk + base * 4)     = lo;
    *(half8*)(Upk + base * 4 + 8) = hi;
}

// ---------------------------------------------------------------------------
// SRU scan over packed U: Upk[m][h][4] = {xt, fp, rp, x} as fp16.
// One coalesced 8B load per step per lane; depth-20 register ring (unrolled,
// compile-time indices -> stays in VGPRs). 1000 = 50 * 20, no tail.
__global__ __launch_bounds__(64) void sru_scan(
    const _Float16* __restrict__ Upk, _Float16* __restrict__ Xout,
    const float* __restrict__ v, const float* __restrict__ bg)
{
    const int gid = blockIdx.x * 64 + threadIdx.x;
    const int b = gid >> 9;
    const int h = gid & 511;
    const float vf = v[h],      vr = v[512 + h];
    const float bf = bg[h],     br = bg[512 + h];

    const _Float16* p = Upk + ((size_t)b * T_ * 512 + h) * 4;
    _Float16* ox = Xout + (size_t)b * T_ * 512 + h;

    half4 buf[20];
    #pragma unroll
    for (int j = 0; j < 20; ++j) buf[j] = *(const half4*)(p + (size_t)j * 2048);

    float c = 0.f;
    for (int t0 = 0; t0 < T_; t0 += 20) {
        #pragma unroll
        for (int j = 0; j < 20; ++j) {
            const int t = t0 + j;
            const half4 cur = buf[j];
            const int tn = t + 20;
            if (tn < T_) buf[j] = *(const half4*)(p + (size_t)tn * 2048);
            const float xt = (float)cur[0];
            const float fp = (float)cur[1];
            const float rp = (float)cur[2];
            const float x  = (float)cur[3];
            const float f  = sigmoid_fast(fp + vf * c + bf);
            const float r  = sigmoid_fast(rp + vr * c + br);
            const float cn = f * c + (1.0f - f) * xt;
            const float hO = r * cn + (1.0f - r) * x;
            ox[(size_t)t * 512] = (_Float16)hO;
            c = cn;
        }
    }
}

// ---------------------------------------------------------------------------
// Fused conv6x6(asym pad 3,2) + maxpool3x3(pad 1) + bias + tanh.
// Conv math in packed fp16 (v_pk_fma_f16): in_s fp16, 648 pk_fma + shifts per
// thread replaces 1296 v_fma_f32. tanh AFTER pool (monotonic). Output k-major.
#define CVW 76   // cv row width (halves)

__global__ __launch_bounds__(320) void conv_pool(
    const _Float16* __restrict__ X, const unsigned int* __restrict__ ckp,
    const float* __restrict__ cb, _Float16* __restrict__ A3)
{
    __shared__ __align__(16) _Float16 in_s[23][80];       // fp16, rows padded to 80
    __shared__ __align__(16) _Float16 cv[9][18][CVW];     // raw conv fp16; -65504 = outside
    const int tid = threadIdx.x;
    int bi = blockIdx.x;
    const int th = bi & 7;  bi >>= 3;
    const int tt = bi % 63;
    const int b  = bi / 63;
    const int t0 = tt * 16, h0 = th * 64;

    for (int i = tid; i < 23 * 76; i += 320) {
        const int r = i / 76, cc = i % 76;
        const int gt = t0 - 4 + r, gh = h0 - 4 + cc;
        _Float16 val = (_Float16)0.f;   // conv zero-padding
        if (gt >= 0 && gt < T_ && gh >= 0 && gh < H_)
            val = X[((size_t)b * T_ + gt) * H_ + gh];
        in_s[r][cc] = val;
    }
    __syncthreads();

    // conv phase: 18 pt x 17 ph-groups = 306 tasks, one per thread
    if (tid < 306) {
        const int pt = tid / 17;        // conv row: ct = t0 - 1 + pt
        const int co = (tid % 17) * 4;  // conv col offset (co % 4 == 0)

        const int ct = t0 - 1 + pt;
        const bool rok = (ct >= 0) && (ct < T_);
        const int chb = h0 - 1 + co;
        const bool ok0 = rok && (chb + 0 >= 0) && (chb + 0 < H_);
        const bool ok1 = rok && (chb + 1 >= 0) && (chb + 1 < H_);
        const bool ok2 = rok && (chb + 2 >= 0) && (chb + 2 < H_);
        const bool ok3 = rok && (chb + 3 >= 0) && (chb + 3 < H_);

        h2 acc0[9], acc1[9];            // (q0,q1) and (q2,q3) accumulators
        #pragma unroll
        for (int k = 0; k < 9; ++k) {
            acc0[k][0] = (_Float16)0.f; acc0[k][1] = (_Float16)0.f;
            acc1[k][0] = (_Float16)0.f; acc1[k][1] = (_Float16)0.f;
        }

        #pragma unroll 1
        for (int ii = 0; ii < 6; ++ii) {
            const unsigned int* rw = (const unsigned int*)&in_s[pt + ii][co];  // 8-B aligned
            const uint2 a01 = *(const uint2*)(rw);
            const uint2 a23 = *(const uint2*)(rw + 2);
            const unsigned int A0 = a01.x, A1v = a01.y, A2 = a23.x, A3v = a23.y;
            const unsigned int A4 = rw[4];
            // misaligned pairs: Mm[i] = halves(co+2i+1, co+2i+2)
            const unsigned int M0 = (A0  >> 16) | (A1v << 16);
            const unsigned int M1 = (A1v >> 16) | (A2  << 16);
            const unsigned int M2 = (A2  >> 16) | (A3v << 16);
            const unsigned int M3 = (A3v >> 16) | (A4  << 16);

            const unsigned int* wt = ckp + ii * 6;   // + k*36 + J, wave-uniform
            #pragma unroll
            for (int k = 0; k < 9; ++k) {
                const unsigned int* wk = wt + k * 36;
                acc0[k] = pkfma(wk[0], A0,  acc0[k]);  acc1[k] = pkfma(wk[0], A1v, acc1[k]); // J=0
                acc0[k] = pkfma(wk[1], M0,  acc0[k]);  acc1[k] = pkfma(wk[1], M1,  acc1[k]); // J=1
                acc0[k] = pkfma(wk[2], A1v, acc0[k]);  acc1[k] = pkfma(wk[2], A2,  acc1[k]); // J=2
                acc0[k] = pkfma(wk[3], M1,  acc0[k]);  acc1[k] = pkfma(wk[3], M2,  acc1[k]); // J=3
                acc0[k] = pkfma(wk[4], A2,  acc0[k]);  acc1[k] = pkfma(wk[4], A3v, acc1[k]); // J=4
                acc0[k] = pkfma(wk[5], M2,  acc0[k]);  acc1[k] = pkfma(wk[5], M3,  acc1[k]); // J=5
            }
        }

        const _Float16 NEG = (_Float16)(-65504.f);
        #pragma unroll
        for (int k = 0; k < 9; ++k) {
            half4 o;
            o[0] = ok0 ? acc0[k][0] : NEG;
            o[1] = ok1 ? acc0[k][1] : NEG;
            o[2] = ok2 ? acc1[k][0] : NEG;
            o[3] = ok3 ? acc1[k][1] : NEG;
            *(half4*)(&cv[k][pt][co]) = o;
        }
    }
    __syncthreads();

    // pool phase: 16 pt x 16 ph-groups of 4 = 256 tasks; bias+tanh here
    if (tid < 256) {
        const int pt = tid >> 4;
        const int gt = t0 + pt;
        if (gt < T_) {
            const int ph = (tid & 15) * 4;
            _Float16* dst = A3 + ((size_t)b * T_ + gt) * KHID + (h0 + ph);
            #pragma unroll
            for (int k = 0; k < 9; ++k) {
                float q0 = -1e30f, q1 = -1e30f, q2 = -1e30f, q3 = -1e30f;
                #pragma unroll
                for (int dr = 0; dr < 3; ++dr) {
                    const _Float16* cr = &cv[k][pt + dr][ph];
                    const half4  a = *(const half4*)(cr);
                    const half2v bq = *(const half2v*)(cr + 4);
                    const float v0 = (float)a[0], v1 = (float)a[1], v2 = (float)a[2];
                    const float v3 = (float)a[3], v4 = (float)bq[0], v5 = (float)bq[1];
                    const float t01 = fmaxf(v1, v2);
                    const float t34 = fmaxf(v3, v4);
                    q0 = fmaxf(q0, fmaxf(v0, t01));
                    q1 = fmaxf(q1, fmaxf(t01, v3));
                    q2 = fmaxf(q2, fmaxf(v2, t34));
                    q3 = fmaxf(q3, fmaxf(t34, v5));
                }
                const float bk = cb[k];
                half4 o;
                o[0] = (_Float16)tanh_fast(q0 + bk);
                o[1] = (_Float16)tanh_fast(q1 + bk);
                o[2] = (_Float16)tanh_fast(q2 + bk);
                o[3] = (_Float16)tanh_fast(q3 + bk);
                *(half4*)(dst + (size_t)k * 512) = o;
            }
        }
    }
}

// ---------------------------------------------------------------------------
extern "C" void kernel_launch(void* const* d_in, const int* in_sizes, int n_in,
                              void* d_out, int out_size, void* d_ws, size_t ws_size,
                              hipStream_t stream) {
    const float* inputs = (const float*)d_in[0];
    const float* W_in   = (const float*)d_in[1];
    const float* b_in   = (const float*)d_in[2];
    const float* W_rnn  = (const float*)d_in[3];
    const float* v_rnn  = (const float*)d_in[4];
    const float* b_rnn  = (const float*)d_in[5];
    const float* conv_k = (const float*)d_in[6];
    const float* conv_b = (const float*)d_in[7];
    const float* W_out  = (const float*)d_in[8];
    const float* b_out  = (const float*)d_in[9];
    float* out = (float*)d_out;

    char* ws = (char*)d_ws;
    size_t off = 0;
    auto take = [&](size_t bytes) -> char* {
        off = (off + 255) & ~(size_t)255;
        char* p = ws + off;
        off += bytes;
        return p;
    };
    // W3T first so it survives; A1..X1 form a dead span at G3 time for Cp alias.
    _Float16* W3T  = (_Float16*)take((size_t)NOUT * KHID * 2);  // W_out[:,257:514)^T, K-permuted
    _Float16* A1   = (_Float16*)take((size_t)M_ * FEATP * 2);   // inputs fp16, padded (dead after G1)
    _Float16* W1T  = (_Float16*)take((size_t)H_ * FEATP * 2);   // W_in^T
    _Float16* W2T0 = (_Float16*)take((size_t)H3 * H_ * 2);      // W_rnn[0]^T
    _Float16* W2T1 = (_Float16*)take((size_t)H3 * H_ * 2);      // W_rnn[1]^T
    _Float16* X0   = (_Float16*)take((size_t)M_ * H_ * 2);      // tanh(G1); scan1 output (X2)
    _Float16* X1   = (_Float16*)take((size_t)M_ * H_ * 2);      // scan0 output
    _Float16* U    = (_Float16*)take(3 * (size_t)M_ * 512 * 2); // SoA U planes (xt,fp,rp)
    _Float16* A3   = (_Float16*)take((size_t)M_ * KHID * 2);    // pooled conv, k-major (k*512+h)
    unsigned int* ckp = (unsigned int*)take(9 * 36 * 4);        // packed dup'd fp16 conv weights
    // Packed U aliases the head of A3 (dead until conv_pool runs; consumed before):
    _Float16* Upk = A3;
    // Split-K partials alias the dead A1..X1 span (49.4 MB < 62.4 MB span):
    float* Cp = (float*)A1;
    _Float16* X2 = X0;  // X0 dead after repack0 -> reuse for scan1 output

    // --- weight/input preprocessing (fp32 -> fp16, transpose to NxK) ---
    {
        size_t n = (size_t)M_ * FEATP;
        convert_inputs<<<dim3((unsigned)((n + 255) / 256)), 256, 0, stream>>>(inputs, A1);
    }
    pack_ck<<<dim3(1), 384, 0, stream>>>(conv_k, ckp);
    transpose_w<<<dim3(25, 16), 256, 0, stream>>>(W_in, W1T, FEAT, H_, H_, 0, FEATP, 0);
    transpose_w<<<dim3(16, 48), 256, 0, stream>>>(W_rnn, W2T0, H_, H3, H3, 0, H_, 0);
    transpose_w<<<dim3(16, 48), 256, 0, stream>>>(W_rnn + (size_t)H_ * H3, W2T1, H_, H3, H3, 0, H_, 0);
    transpose_w<<<dim3(144, 9), 256, 0, stream>>>(W_out, W3T, KHID, NOUT, FEAT, 257, KHID, 1);

    const unsigned nrep = (unsigned)(((size_t)M_ * 128 + 255) / 256);

    // --- G1: X0 = tanh(inputs @ W_in + b_in) ---
    gemm_kernel<0><<<dim3(125, 4), 256, 0, stream>>>(A1, W1T, FEATP, 25, H_, X0, nullptr, H_, b_in);

    // --- SRU layer 0: U-GEMM (SoA) -> repack -> scan ---
    gemm_kernel<1><<<dim3(125, 12), 256, 0, stream>>>(X0, W2T0, H_, 16, H3, U, nullptr, 0, nullptr);
    repack_u<<<dim3(nrep), 256, 0, stream>>>(U, X0, Upk);
    sru_scan<<<dim3(128), 64, 0, stream>>>(Upk, X1, v_rnn, b_rnn);

    // --- SRU layer 1 ---
    gemm_kernel<1><<<dim3(125, 12), 256, 0, stream>>>(X1, W2T1, H_, 16, H3, U, nullptr, 0, nullptr);
    repack_u<<<dim3(nrep), 256, 0, stream>>>(U, X1, Upk);
    sru_scan<<<dim3(128), 64, 0, stream>>>(Upk, X2, v_rnn + 1024, b_rnn + 1024);

    // --- conv + maxpool + bias + tanh fused, producing final-GEMM A matrix ---
    conv_pool<<<dim3(16 * 63 * 8), 320, 0, stream>>>(X2, ckp, conv_b, A3);

    // --- G3 split-K: Cp[z] = A3 @ W3T (K-slice z), then reduce+sigmoid+mask ---
    gemm_kernel<3><<<dim3(125, 3, KSLICES), 256, 0, stream>>>(A3, W3T, KHID, 144 / KSLICES, NOUT, nullptr, Cp, 0, nullptr);
    {
        const unsigned nred = (unsigned)(((size_t)M_ * NOUT + 255) / 256);
        reduce_out<<<dim3(nred), 256, 0, stream>>>(Cp, b_out + 257, inputs, out);
    }
}

// Round 5
// 803.129 us; speedup vs baseline: 1.8495x; 1.0163x over previous
//
#include <hip/hip_runtime.h>
#include <hip/hip_bf16.h>

// Problem constants
#define B_    16
#define T_    1000
#define FEAT  771
#define FEATP 800      // 771 padded to 25*32 (exact BK multiple -> guard-free GEMM)
#define H_    512
#define H3    1536
#define KN_   9
#define KHID  4608     // H*KN
#define M_    16000    // B*T
#define NOUT  257      // output column slice [257:514)
#define KSLICES 3      // split-K factor for the final GEMM

typedef _Float16 half8 __attribute__((ext_vector_type(8)));
typedef _Float16 half4 __attribute__((ext_vector_type(4)));
typedef _Float16 half2v __attribute__((ext_vector_type(2)));
typedef _Float16 h2 __attribute__((ext_vector_type(2)));
typedef float    floatx4 __attribute__((ext_vector_type(4)));

// tanh(z) = 1 - 2/(1+e^{2z})  — saturates correctly at +/-inf, no NaN
__device__ inline float tanh_fast(float z) {
    return 1.0f - 2.0f / (1.0f + __expf(2.0f * z));
}
__device__ inline float sigmoid_fast(float z) {
    return 1.0f / (1.0f + __expf(-z));
}

// async global->LDS, 16B per lane; LDS dst must be wave-uniform base
__device__ inline void gload16(const _Float16* g, _Float16* l) {
    __builtin_amdgcn_global_load_lds(
        (const __attribute__((address_space(1))) void*)g,
        (__attribute__((address_space(3))) void*)l, 16, 0, 0);
}

// Guaranteed packed fp16 ops (compiler was scalarizing h2 arithmetic):
// acc = w*x + acc, elementwise on 2 halves; w is wave-uniform (SGPR src0).
__device__ inline void pk_fma_acc(unsigned& acc, unsigned w, unsigned x) {
    asm("v_pk_fma_f16 %0, %1, %2, %0" : "+v"(acc) : "s"(w), "v"(x));
}
__device__ inline unsigned pk_max(unsigned a, unsigned b) {
    unsigned d;
    asm("v_pk_max_f16 %0, %1, %2" : "=v"(d) : "v"(a), "v"(b));
    return d;
}

// ---------------------------------------------------------------------------
// fp32 -> fp16 convert of inputs, padding rows 771 -> 800 with zeros
__global__ void convert_inputs(const float* __restrict__ in, _Float16* __restrict__ A1) {
    size_t i = (size_t)blockIdx.x * 256 + threadIdx.x;
    if (i >= (size_t)M_ * FEATP) return;
    size_t r = i / FEATP;
    int   cc = (int)(i % FEATP);
    A1[i] = (cc < FEAT) ? (_Float16)in[r * FEAT + cc] : (_Float16)0.f;
}

// ---------------------------------------------------------------------------
// Pack conv weights into dup'd half2 u32: ckp[i] = (h(ck[i]), h(ck[i]))
__global__ void pack_ck(const float* __restrict__ ck, unsigned int* __restrict__ ckp) {
    const int i = threadIdx.x;
    if (i < 9 * 36) {
        const _Float16 w = (_Float16)ck[i];
        const unsigned short u = __builtin_bit_cast(unsigned short, w);
        ckp[i] = ((unsigned int)u << 16) | u;
    }
}

// ---------------------------------------------------------------------------
// LDS-tiled transpose+convert: Wt[n*Kp + kidx] = (k<K) ? W[k*ldw + coloff + n] : 0
// perm9: kidx = (k%9)*512 + k/9  (k-major planes for the conv output layout)
__global__ __launch_bounds__(256) void transpose_w(
    const float* __restrict__ W, _Float16* __restrict__ Wt,
    int K, int N, int ldw, int coloff, int Kp, int perm9)
{
    __shared__ float tile[32][33];
    const int kb = blockIdx.x * 32;
    const int nb = blockIdx.y * 32;
    const int tx = threadIdx.x & 31;
    const int ty = threadIdx.x >> 5;   // 0..7
    #pragma unroll
    for (int r = ty; r < 32; r += 8) {
        const int k = kb + r, n = nb + tx;
        tile[r][tx] = (k < K && n < N) ? W[(size_t)k * ldw + coloff + n] : 0.f;
    }
    __syncthreads();
    #pragma unroll
    for (int r = ty; r < 32; r += 8) {
        const int n = nb + r, k = kb + tx;
        if (n < N && k < Kp) {
            size_t kidx = (size_t)k;
            if (perm9) kidx = (size_t)(k % 9) * 512 + (size_t)(k / 9);
            Wt[(size_t)n * Kp + kidx] = (_Float16)tile[tx][r];
        }
    }
}

// ---------------------------------------------------------------------------
// Tiled fp16 MFMA GEMM: C[M x N] = A[M x Kp] * Bt[N x Kp]^T, fp32 accumulate.
// 128x128 block tile, BK=32, 4 waves (2x2), each wave 4x4 of 16x16x32 MFMA.
// 2-phase prefetch: double-buffered LDS, tile k+1 staged via global_load_lds
// BEFORE computing tile k; one vmcnt(0)+raw-barrier per K-step (loads overlap
// ds_read+MFMA of the current tile).
template <int EPI>
__global__ __launch_bounds__(256) void gemm_kernel(
    const _Float16* __restrict__ A, const _Float16* __restrict__ Bt,
    int Kp, int nk, int Nb,
    _Float16* __restrict__ Ch, float* __restrict__ Cf, int ldc,
    const float* __restrict__ bias)
{
    __shared__ __align__(16) _Float16 As[2][128][32];
    __shared__ __align__(16) _Float16 Bs[2][128][32];

    const int tid  = threadIdx.x;
    const int m0   = blockIdx.x * 128;
    const int n0   = blockIdx.y * 128;
    const int koff = blockIdx.z * (nk << 5);   // K-slice origin
    const int wave = tid >> 6;
    const int lane = tid & 63;
    const int wr   = (wave >> 1) << 6;   // wave row offset (0/64)
    const int wc   = (wave & 1) << 6;    // wave col offset (0/64)
    const int lrow = lane & 15;
    const int lq   = lane >> 4;          // 0..3

    // staging: wave w stages rows [w*32, w*32+32), 2 instrs per matrix
    const int srow0  = wave * 32 + (lane >> 2);   // rows for instr 0
    const int schunk = (lane & 3) * 8;            // halves within row
    const _Float16* aSrc = A  + (size_t)(m0 + srow0) * Kp + koff + schunk;
    const _Float16* bSrc = Bt + (size_t)(n0 + srow0) * Kp + koff + schunk;
    const size_t rstep = (size_t)16 * Kp;

    floatx4 acc[4][4];
    #pragma unroll
    for (int i = 0; i < 4; ++i)
        #pragma unroll
        for (int j = 0; j < 4; ++j)
            #pragma unroll
            for (int r = 0; r < 4; ++r) acc[i][j][r] = 0.f;

    // prologue: stage tile 0 into buffer 0
    gload16(aSrc,         &As[0][wave * 32][0]);
    gload16(aSrc + rstep, &As[0][wave * 32 + 16][0]);
    gload16(bSrc,         &Bs[0][wave * 32][0]);
    gload16(bSrc + rstep, &Bs[0][wave * 32 + 16][0]);
    asm volatile("s_waitcnt vmcnt(0)" ::: "memory");
    __builtin_amdgcn_s_barrier();

    for (int kc = 0; kc < nk; ++kc) {
        const int cur = kc & 1;
        if (kc + 1 < nk) {   // prefetch next tile into the other buffer
            const _Float16* a2 = aSrc + (size_t)(kc + 1) * 32;
            const _Float16* b2 = bSrc + (size_t)(kc + 1) * 32;
            gload16(a2,         &As[cur ^ 1][wave * 32][0]);
            gload16(a2 + rstep, &As[cur ^ 1][wave * 32 + 16][0]);
            gload16(b2,         &Bs[cur ^ 1][wave * 32][0]);
            gload16(b2 + rstep, &Bs[cur ^ 1][wave * 32 + 16][0]);
        }

        half8 af[4], bfr[4];
        #pragma unroll
        for (int i = 0; i < 4; ++i) af[i]  = *(const half8*)(&As[cur][wr + i * 16 + lrow][lq * 8]);
        #pragma unroll
        for (int j = 0; j < 4; ++j) bfr[j] = *(const half8*)(&Bs[cur][wc + j * 16 + lrow][lq * 8]);
        #pragma unroll
        for (int i = 0; i < 4; ++i)
            #pragma unroll
            for (int j = 0; j < 4; ++j)
                acc[i][j] = __builtin_amdgcn_mfma_f32_16x16x32_f16(af[i], bfr[j], acc[i][j], 0, 0, 0);

        if (kc + 1 < nk) {
            asm volatile("s_waitcnt vmcnt(0)" ::: "memory");
            __builtin_amdgcn_s_barrier();
        }
    }

    // Epilogue: C/D layout col=lane&15, row=quad*4+reg
    #pragma unroll
    for (int j = 0; j < 4; ++j) {
        const int col = n0 + wc + j * 16 + lrow;
        if (col >= Nb) continue;
        #pragma unroll
        for (int i = 0; i < 4; ++i) {
            #pragma unroll
            for (int r = 0; r < 4; ++r) {
                const int row = m0 + wr + i * 16 + lq * 4 + r;
                float v = acc[i][j][r];
                if constexpr (EPI == 0) {
                    float z = v + bias[col];
                    Ch[(size_t)row * ldc + col] = (_Float16)tanh_fast(z);
                } else if constexpr (EPI == 1) {
                    Ch[(size_t)(col >> 9) * ((size_t)M_ * 512) + (size_t)row * 512 + (col & 511)] = (_Float16)v;
                } else {
                    Cf[(size_t)blockIdx.z * M_ * NOUT + (size_t)row * NOUT + col] = v;
                }
            }
        }
    }
}

// ---------------------------------------------------------------------------
// Split-K reduction + sigmoid epilogue for the final GEMM.
__global__ __launch_bounds__(256) void reduce_out(
    const float* __restrict__ Cp, const float* __restrict__ bias,
    const float* __restrict__ aux, float* __restrict__ out)
{
    const size_t i = (size_t)blockIdx.x * 256 + threadIdx.x;
    if (i >= (size_t)M_ * NOUT) return;
    const int row = (int)(i / NOUT);
    const int col = (int)(i % NOUT);
    float s = Cp[i] + Cp[i + (size_t)M_ * NOUT] + Cp[i + 2 * (size_t)M_ * NOUT];
    out[i] = sigmoid_fast(s + bias[col]) * aux[(size_t)row * FEAT + 257 + col];
}

// ---------------------------------------------------------------------------
// Repack SoA U planes + X into packed Upk[m][h][4] = {xt, fp, rp, x} fp16.
// Keeps the scan at ONE 8-B load/step (20 outstanding <= vmcnt limit);
// direct 4-stream scan reads collapse the prefetch pipeline (measured r3).
__global__ __launch_bounds__(256) void repack_u(
    const _Float16* __restrict__ U,   // 3 planes [M][512]
    const _Float16* __restrict__ X,   // [M][512] dense layer input
    _Float16* __restrict__ Upk)       // [M][512][4]
{
    const size_t i = (size_t)blockIdx.x * 256 + threadIdx.x;  // over M*128 4-h groups
    if (i >= (size_t)M_ * 128) return;
    const size_t base = i << 2;       // = m*512 + h (h multiple of 4)
    const half4 a = *(const half4*)(U + base);
    const half4 f = *(const half4*)(U + (size_t)M_ * 512 + base);
    const half4 r = *(const half4*)(U + 2 * (size_t)M_ * 512 + base);
    const half4 x = *(const half4*)(X + base);
    half8 lo, hi;
    lo[0] = a[0]; lo[1] = f[0]; lo[2] = r[0]; lo[3] = x[0];
    lo[4] = a[1]; lo[5] = f[1]; lo[6] = r[1]; lo[7] = x[1];
    hi[0] = a[2]; hi[1] = f[2]; hi[2] = r[2]; hi[3] = x[2];
    hi[4] = a[3]; hi[5] = f[3]; hi[6] = r[3]; hi[7] = x[3];
    *(half8*)(Upk + base * 4)     = lo;
    *(half8*)(Upk + base * 4 + 8) = hi;
}

// ---------------------------------------------------------------------------
// SRU scan over packed U: Upk[m][h][4] = {xt, fp, rp, x} as fp16.
__global__ __launch_bounds__(64) void sru_scan(
    const _Float16* __restrict__ Upk, _Float16* __restrict__ Xout,
    const float* __restrict__ v, const float* __restrict__ bg)
{
    const int gid = blockIdx.x * 64 + threadIdx.x;
    const int b = gid >> 9;
    const int h = gid & 511;
    const float vf = v[h],      vr = v[512 + h];
    const float bf = bg[h],     br = bg[512 + h];

    const _Float16* p = Upk + ((size_t)b * T_ * 512 + h) * 4;
    _Float16* ox = Xout + (size_t)b * T_ * 512 + h;

    half4 buf[20];
    #pragma unroll
    for (int j = 0; j < 20; ++j) buf[j] = *(const half4*)(p + (size_t)j * 2048);

    float c = 0.f;
    for (int t0 = 0; t0 < T_; t0 += 20) {
        #pragma unroll
        for (int j = 0; j < 20; ++j) {
            const int t = t0 + j;
            const half4 cur = buf[j];
            const int tn = t + 20;
            if (tn < T_) buf[j] = *(const half4*)(p + (size_t)tn * 2048);
            const float xt = (float)cur[0];
            const float fp = (float)cur[1];
            const float rp = (float)cur[2];
            const float x  = (float)cur[3];
            const float f  = sigmoid_fast(fp + vf * c + bf);
            const float r  = sigmoid_fast(rp + vr * c + br);
            const float cn = f * c + (1.0f - f) * xt;
            const float hO = r * cn + (1.0f - r) * x;
            ox[(size_t)t * 512] = (_Float16)hO;
            c = cn;
        }
    }
}

// ---------------------------------------------------------------------------
// Fused conv6x6(asym pad 3,2) + maxpool3x3(pad 1) + bias + tanh.
// Conv + pool math in GUARANTEED packed fp16 via inline asm (v_pk_fma_f16 /
// v_pk_max_f16) — the ext-vector h2 path was scalarizing (r4 audit: measured
// VALU-busy ~2.7x the source-level op count). alignbit for shifted windows.
// tanh AFTER pool (monotonic). Output k-major (k*512+h).
#define CVW 76   // cv row width (halves)

__global__ __launch_bounds__(320) void conv_pool(
    const _Float16* __restrict__ X, const unsigned int* __restrict__ ckp,
    const float* __restrict__ cb, _Float16* __restrict__ A3)
{
    __shared__ __align__(16) _Float16 in_s[23][80];       // fp16, rows padded to 80
    __shared__ __align__(16) _Float16 cv[9][18][CVW];     // raw conv fp16; -65504 = outside
    const int tid = threadIdx.x;
    int bi = blockIdx.x;
    const int th = bi & 7;  bi >>= 3;
    const int tt = bi % 63;
    const int b  = bi / 63;
    const int t0 = tt * 16, h0 = th * 64;

    for (int i = tid; i < 23 * 76; i += 320) {
        const int r = i / 76, cc = i % 76;
        const int gt = t0 - 4 + r, gh = h0 - 4 + cc;
        _Float16 val = (_Float16)0.f;   // conv zero-padding
        if (gt >= 0 && gt < T_ && gh >= 0 && gh < H_)
            val = X[((size_t)b * T_ + gt) * H_ + gh];
        in_s[r][cc] = val;
    }
    __syncthreads();

    // conv phase: 18 pt x 17 ph-groups = 306 tasks, one per thread
    if (tid < 306) {
        const int pt = tid / 17;        // conv row: ct = t0 - 1 + pt
        const int co = (tid % 17) * 4;  // conv col offset (co % 4 == 0)

        const int ct = t0 - 1 + pt;
        const bool rok = (ct >= 0) && (ct < T_);
        const int chb = h0 - 1 + co;
        const bool ok0 = rok && (chb + 0 >= 0) && (chb + 0 < H_);
        const bool ok1 = rok && (chb + 1 >= 0) && (chb + 1 < H_);
        const bool ok2 = rok && (chb + 2 >= 0) && (chb + 2 < H_);
        const bool ok3 = rok && (chb + 3 >= 0) && (chb + 3 < H_);

        unsigned acc0[9], acc1[9];      // packed (q0,q1) and (q2,q3), fp16 pairs
        #pragma unroll
        for (int k = 0; k < 9; ++k) { acc0[k] = 0u; acc1[k] = 0u; }

        #pragma unroll 1
        for (int ii = 0; ii < 6; ++ii) {
            const unsigned int* rw = (const unsigned int*)&in_s[pt + ii][co];  // 8-B aligned
            const uint2 a01 = *(const uint2*)(rw);
            const uint2 a23 = *(const uint2*)(rw + 2);
            const unsigned int A0 = a01.x, A1v = a01.y, A2 = a23.x, A3v = a23.y;
            const unsigned int A4 = rw[4];
            // misaligned pairs (1 instr each): M[i] = halves(co+2i+1, co+2i+2)
            const unsigned int M0 = __builtin_amdgcn_alignbit(A1v, A0, 16);
            const unsigned int M1 = __builtin_amdgcn_alignbit(A2, A1v, 16);
            const unsigned int M2 = __builtin_amdgcn_alignbit(A3v, A2, 16);
            const unsigned int M3 = __builtin_amdgcn_alignbit(A4, A3v, 16);

            const unsigned int* wt = ckp + ii * 6;   // + k*36 + J, wave-uniform (SGPR)
            #pragma unroll
            for (int k = 0; k < 9; ++k) {
                const unsigned int* wk = wt + k * 36;
                pk_fma_acc(acc0[k], wk[0], A0);   pk_fma_acc(acc1[k], wk[0], A1v);  // J=0
                pk_fma_acc(acc0[k], wk[1], M0);   pk_fma_acc(acc1[k], wk[1], M1);   // J=1
                pk_fma_acc(acc0[k], wk[2], A1v);  pk_fma_acc(acc1[k], wk[2], A2);   // J=2
                pk_fma_acc(acc0[k], wk[3], M1);   pk_fma_acc(acc1[k], wk[3], M2);   // J=3
                pk_fma_acc(acc0[k], wk[4], A2);   pk_fma_acc(acc1[k], wk[4], A3v);  // J=4
                pk_fma_acc(acc0[k], wk[5], M2);   pk_fma_acc(acc1[k], wk[5], M3);   // J=5
            }
        }

        const _Float16 NEG = (_Float16)(-65504.f);
        #pragma unroll
        for (int k = 0; k < 9; ++k) {
            const h2 pa = __builtin_bit_cast(h2, acc0[k]);
            const h2 pb = __builtin_bit_cast(h2, acc1[k]);
            half4 o;
            o[0] = ok0 ? pa[0] : NEG;
            o[1] = ok1 ? pa[1] : NEG;
            o[2] = ok2 ? pb[0] : NEG;
            o[3] = ok3 ? pb[1] : NEG;
            *(half4*)(&cv[k][pt][co]) = o;
        }
    }
    __syncthreads();

    // pool phase: 16 pt x 16 ph-groups of 4 = 256 tasks; packed fp16 max,
    // then bias+tanh in fp32 on the 4 pooled values only.
    if (tid < 256) {
        const int pt = tid >> 4;
        const int gt = t0 + pt;
        if (gt < T_) {
            const int ph = (tid & 15) * 4;
            _Float16* dst = A3 + ((size_t)b * T_ + gt) * KHID + (h0 + ph);
            #pragma unroll
            for (int k = 0; k < 9; ++k) {
                unsigned q01 = 0xFC00FC00u, q23 = 0xFC00FC00u;   // (-inf,-inf) fp16
                #pragma unroll
                for (int dr = 0; dr < 3; ++dr) {
                    const unsigned* cr = (const unsigned*)&cv[k][pt + dr][ph];
                    const uint2 w01 = *(const uint2*)(cr);     // (v0,v1),(v2,v3)
                    const unsigned w2 = cr[2];                 // (v4,v5)
                    const unsigned m12 = __builtin_amdgcn_alignbit(w01.y, w01.x, 16); // (v1,v2)
                    const unsigned m34 = __builtin_amdgcn_alignbit(w2, w01.y, 16);    // (v3,v4)
                    q01 = pk_max(q01, pk_max(pk_max(w01.x, m12), w01.y));
                    q23 = pk_max(q23, pk_max(pk_max(w01.y, m34), w2));
                }
                const h2 qa = __builtin_bit_cast(h2, q01);
                const h2 qb = __builtin_bit_cast(h2, q23);
                const float bk = cb[k];
                half4 o;
                o[0] = (_Float16)tanh_fast((float)qa[0] + bk);
                o[1] = (_Float16)tanh_fast((float)qa[1] + bk);
                o[2] = (_Float16)tanh_fast((float)qb[0] + bk);
                o[3] = (_Float16)tanh_fast((float)qb[1] + bk);
                *(half4*)(dst + (size_t)k * 512) = o;
            }
        }
    }
}

// ---------------------------------------------------------------------------
extern "C" void kernel_launch(void* const* d_in, const int* in_sizes, int n_in,
                              void* d_out, int out_size, void* d_ws, size_t ws_size,
                              hipStream_t stream) {
    const float* inputs = (const float*)d_in[0];
    const float* W_in   = (const float*)d_in[1];
    const float* b_in   = (const float*)d_in[2];
    const float* W_rnn  = (const float*)d_in[3];
    const float* v_rnn  = (const float*)d_in[4];
    const float* b_rnn  = (const float*)d_in[5];
    const float* conv_k = (const float*)d_in[6];
    const float* conv_b = (const float*)d_in[7];
    const float* W_out  = (const float*)d_in[8];
    const float* b_out  = (const float*)d_in[9];
    float* out = (float*)d_out;

    char* ws = (char*)d_ws;
    size_t off = 0;
    auto take = [&](size_t bytes) -> char* {
        off = (off + 255) & ~(size_t)255;
        char* p = ws + off;
        off += bytes;
        return p;
    };
    // W3T first so it survives; A1..X1 form a dead span at G3 time for Cp alias.
    _Float16* W3T  = (_Float16*)take((size_t)NOUT * KHID * 2);  // W_out[:,257:514)^T, K-permuted
    _Float16* A1   = (_Float16*)take((size_t)M_ * FEATP * 2);   // inputs fp16, padded (dead after G1)
    _Float16* W1T  = (_Float16*)take((size_t)H_ * FEATP * 2);   // W_in^T
    _Float16* W2T0 = (_Float16*)take((size_t)H3 * H_ * 2);      // W_rnn[0]^T
    _Float16* W2T1 = (_Float16*)take((size_t)H3 * H_ * 2);      // W_rnn[1]^T
    _Float16* X0   = (_Float16*)take((size_t)M_ * H_ * 2);      // tanh(G1); scan1 output (X2)
    _Float16* X1   = (_Float16*)take((size_t)M_ * H_ * 2);      // scan0 output
    _Float16* U    = (_Float16*)take(3 * (size_t)M_ * 512 * 2); // SoA U planes (xt,fp,rp)
    _Float16* A3   = (_Float16*)take((size_t)M_ * KHID * 2);    // pooled conv, k-major (k*512+h)
    unsigned int* ckp = (unsigned int*)take(9 * 36 * 4);        // packed dup'd fp16 conv weights
    // Packed U aliases the head of A3 (dead until conv_pool runs; consumed before):
    _Float16* Upk = A3;
    // Split-K partials alias the dead A1..X1 span (49.4 MB < 62.4 MB span):
    float* Cp = (float*)A1;
    _Float16* X2 = X0;  // X0 dead after repack0 -> reuse for scan1 output

    // --- weight/input preprocessing (fp32 -> fp16, transpose to NxK) ---
    {
        size_t n = (size_t)M_ * FEATP;
        convert_inputs<<<dim3((unsigned)((n + 255) / 256)), 256, 0, stream>>>(inputs, A1);
    }
    pack_ck<<<dim3(1), 384, 0, stream>>>(conv_k, ckp);
    transpose_w<<<dim3(25, 16), 256, 0, stream>>>(W_in, W1T, FEAT, H_, H_, 0, FEATP, 0);
    transpose_w<<<dim3(16, 48), 256, 0, stream>>>(W_rnn, W2T0, H_, H3, H3, 0, H_, 0);
    transpose_w<<<dim3(16, 48), 256, 0, stream>>>(W_rnn + (size_t)H_ * H3, W2T1, H_, H3, H3, 0, H_, 0);
    transpose_w<<<dim3(144, 9), 256, 0, stream>>>(W_out, W3T, KHID, NOUT, FEAT, 257, KHID, 1);

    const unsigned nrep = (unsigned)(((size_t)M_ * 128 + 255) / 256);

    // --- G1: X0 = tanh(inputs @ W_in + b_in) ---
    gemm_kernel<0><<<dim3(125, 4), 256, 0, stream>>>(A1, W1T, FEATP, 25, H_, X0, nullptr, H_, b_in);

    // --- SRU layer 0: U-GEMM (SoA) -> repack -> scan ---
    gemm_kernel<1><<<dim3(125, 12), 256, 0, stream>>>(X0, W2T0, H_, 16, H3, U, nullptr, 0, nullptr);
    repack_u<<<dim3(nrep), 256, 0, stream>>>(U, X0, Upk);
    sru_scan<<<dim3(128), 64, 0, stream>>>(Upk, X1, v_rnn, b_rnn);

    // --- SRU layer 1 ---
    gemm_kernel<1><<<dim3(125, 12), 256, 0, stream>>>(X1, W2T1, H_, 16, H3, U, nullptr, 0, nullptr);
    repack_u<<<dim3(nrep), 256, 0, stream>>>(U, X1, Upk);
    sru_scan<<<dim3(128), 64, 0, stream>>>(Upk, X2, v_rnn + 1024, b_rnn + 1024);

    // --- conv + maxpool + bias + tanh fused, producing final-GEMM A matrix ---
    conv_pool<<<dim3(16 * 63 * 8), 320, 0, stream>>>(X2, ckp, conv_b, A3);

    // --- G3 split-K: Cp[z] = A3 @ W3T (K-slice z), then reduce+sigmoid+mask ---
    gemm_kernel<3><<<dim3(125, 3, KSLICES), 256, 0, stream>>>(A3, W3T, KHID, 144 / KSLICES, NOUT, nullptr, Cp, 0, nullptr);
    {
        const unsigned nred = (unsigned)(((size_t)M_ * NOUT + 255) / 256);
        reduce_out<<<dim3(nred), 256, 0, stream>>>(Cp, b_out + 257, inputs, out);
    }
}

// Round 6
// 727.048 us; speedup vs baseline: 2.0431x; 1.1046x over previous
//
#include <hip/hip_runtime.h>
#include <hip/hip_bf16.h>

// Problem constants
#define B_    16
#define T_    1000
#define FEAT  771
#define FEATP 800      // 771 padded to 25*32 (exact BK multiple -> guard-free GEMM)
#define H_    512
#define H3    1536
#define KN_   9
#define KHID  4608     // H*KN
#define M_    16000    // B*T
#define NOUT  257      // output column slice [257:514)
#define KSLICES 3      // split-K factor for the final GEMM

typedef _Float16 half8 __attribute__((ext_vector_type(8)));
typedef _Float16 half4 __attribute__((ext_vector_type(4)));
typedef _Float16 half2v __attribute__((ext_vector_type(2)));
typedef _Float16 h2 __attribute__((ext_vector_type(2)));
typedef float    floatx4 __attribute__((ext_vector_type(4)));

// tanh(z) = 1 - 2/(1+e^{2z})  — saturates correctly at +/-inf, no NaN
__device__ inline float tanh_fast(float z) {
    return 1.0f - 2.0f / (1.0f + __expf(2.0f * z));
}
__device__ inline float sigmoid_fast(float z) {
    return 1.0f / (1.0f + __expf(-z));
}

// async global->LDS, 16B per lane; LDS dst must be wave-uniform base
__device__ inline void gload16(const _Float16* g, _Float16* l) {
    __builtin_amdgcn_global_load_lds(
        (const __attribute__((address_space(1))) void*)g,
        (__attribute__((address_space(3))) void*)l, 16, 0, 0);
}

// Guaranteed packed fp16 ops; w is wave-uniform (SGPR src0).
__device__ inline void pk_fma_acc(unsigned& acc, unsigned w, unsigned x) {
    asm("v_pk_fma_f16 %0, %1, %2, %0" : "+v"(acc) : "s"(w), "v"(x));
}
__device__ inline unsigned pk_max(unsigned a, unsigned b) {
    unsigned d;
    asm("v_pk_max_f16 %0, %1, %2" : "=v"(d) : "v"(a), "v"(b));
    return d;
}

// ---------------------------------------------------------------------------
// fp32 -> fp16 convert of inputs, padding rows 771 -> 800 with zeros
__global__ void convert_inputs(const float* __restrict__ in, _Float16* __restrict__ A1) {
    size_t i = (size_t)blockIdx.x * 256 + threadIdx.x;
    if (i >= (size_t)M_ * FEATP) return;
    size_t r = i / FEATP;
    int   cc = (int)(i % FEATP);
    A1[i] = (cc < FEAT) ? (_Float16)in[r * FEAT + cc] : (_Float16)0.f;
}

// ---------------------------------------------------------------------------
// Pack conv weights into dup'd half2 u32: ckp[i] = (h(ck[i]), h(ck[i]))
__global__ void pack_ck(const float* __restrict__ ck, unsigned int* __restrict__ ckp) {
    const int i = threadIdx.x;
    if (i < 9 * 36) {
        const _Float16 w = (_Float16)ck[i];
        const unsigned short u = __builtin_bit_cast(unsigned short, w);
        ckp[i] = ((unsigned int)u << 16) | u;
    }
}

// ---------------------------------------------------------------------------
// LDS-tiled transpose+convert: Wt[n*Kp + kidx] = (k<K) ? W[k*ldw + coloff + n] : 0
// perm9: kidx = (k%9)*512 + k/9  (k-major planes for the conv output layout)
__global__ __launch_bounds__(256) void transpose_w(
    const float* __restrict__ W, _Float16* __restrict__ Wt,
    int K, int N, int ldw, int coloff, int Kp, int perm9)
{
    __shared__ float tile[32][33];
    const int kb = blockIdx.x * 32;
    const int nb = blockIdx.y * 32;
    const int tx = threadIdx.x & 31;
    const int ty = threadIdx.x >> 5;   // 0..7
    #pragma unroll
    for (int r = ty; r < 32; r += 8) {
        const int k = kb + r, n = nb + tx;
        tile[r][tx] = (k < K && n < N) ? W[(size_t)k * ldw + coloff + n] : 0.f;
    }
    __syncthreads();
    #pragma unroll
    for (int r = ty; r < 32; r += 8) {
        const int n = nb + r, k = kb + tx;
        if (n < N && k < Kp) {
            size_t kidx = (size_t)k;
            if (perm9) kidx = (size_t)(k % 9) * 512 + (size_t)(k / 9);
            Wt[(size_t)n * Kp + kidx] = (_Float16)tile[tx][r];
        }
    }
}

// ---------------------------------------------------------------------------
// Tiled fp16 MFMA GEMM: C[M x N] = A[M x Kp] * Bt[N x Kp]^T, fp32 accumulate.
// 128x128 block tile, BK=32, 4 waves (2x2), each wave 4x4 of 16x16x32 MFMA.
// 2-phase prefetch: double-buffered LDS, tile k+1 staged via global_load_lds
// BEFORE computing tile k; one vmcnt(0)+raw-barrier per K-step.
template <int EPI>
__global__ __launch_bounds__(256) void gemm_kernel(
    const _Float16* __restrict__ A, const _Float16* __restrict__ Bt,
    int Kp, int nk, int Nb,
    _Float16* __restrict__ Ch, float* __restrict__ Cf, int ldc,
    const float* __restrict__ bias)
{
    __shared__ __align__(16) _Float16 As[2][128][32];
    __shared__ __align__(16) _Float16 Bs[2][128][32];

    const int tid  = threadIdx.x;
    const int m0   = blockIdx.x * 128;
    const int n0   = blockIdx.y * 128;
    const int koff = blockIdx.z * (nk << 5);   // K-slice origin
    const int wave = tid >> 6;
    const int lane = tid & 63;
    const int wr   = (wave >> 1) << 6;   // wave row offset (0/64)
    const int wc   = (wave & 1) << 6;    // wave col offset (0/64)
    const int lrow = lane & 15;
    const int lq   = lane >> 4;          // 0..3

    // staging: wave w stages rows [w*32, w*32+32), 2 instrs per matrix
    const int srow0  = wave * 32 + (lane >> 2);   // rows for instr 0
    const int schunk = (lane & 3) * 8;            // halves within row
    const _Float16* aSrc = A  + (size_t)(m0 + srow0) * Kp + koff + schunk;
    const _Float16* bSrc = Bt + (size_t)(n0 + srow0) * Kp + koff + schunk;
    const size_t rstep = (size_t)16 * Kp;

    floatx4 acc[4][4];
    #pragma unroll
    for (int i = 0; i < 4; ++i)
        #pragma unroll
        for (int j = 0; j < 4; ++j)
            #pragma unroll
            for (int r = 0; r < 4; ++r) acc[i][j][r] = 0.f;

    // prologue: stage tile 0 into buffer 0
    gload16(aSrc,         &As[0][wave * 32][0]);
    gload16(aSrc + rstep, &As[0][wave * 32 + 16][0]);
    gload16(bSrc,         &Bs[0][wave * 32][0]);
    gload16(bSrc + rstep, &Bs[0][wave * 32 + 16][0]);
    asm volatile("s_waitcnt vmcnt(0)" ::: "memory");
    __builtin_amdgcn_s_barrier();

    for (int kc = 0; kc < nk; ++kc) {
        const int cur = kc & 1;
        if (kc + 1 < nk) {   // prefetch next tile into the other buffer
            const _Float16* a2 = aSrc + (size_t)(kc + 1) * 32;
            const _Float16* b2 = bSrc + (size_t)(kc + 1) * 32;
            gload16(a2,         &As[cur ^ 1][wave * 32][0]);
            gload16(a2 + rstep, &As[cur ^ 1][wave * 32 + 16][0]);
            gload16(b2,         &Bs[cur ^ 1][wave * 32][0]);
            gload16(b2 + rstep, &Bs[cur ^ 1][wave * 32 + 16][0]);
        }

        half8 af[4], bfr[4];
        #pragma unroll
        for (int i = 0; i < 4; ++i) af[i]  = *(const half8*)(&As[cur][wr + i * 16 + lrow][lq * 8]);
        #pragma unroll
        for (int j = 0; j < 4; ++j) bfr[j] = *(const half8*)(&Bs[cur][wc + j * 16 + lrow][lq * 8]);
        #pragma unroll
        for (int i = 0; i < 4; ++i)
            #pragma unroll
            for (int j = 0; j < 4; ++j)
                acc[i][j] = __builtin_amdgcn_mfma_f32_16x16x32_f16(af[i], bfr[j], acc[i][j], 0, 0, 0);

        if (kc + 1 < nk) {
            asm volatile("s_waitcnt vmcnt(0)" ::: "memory");
            __builtin_amdgcn_s_barrier();
        }
    }

    // Epilogue: C/D layout col=lane&15, row=quad*4+reg
    #pragma unroll
    for (int j = 0; j < 4; ++j) {
        const int col = n0 + wc + j * 16 + lrow;
        if (col >= Nb) continue;
        #pragma unroll
        for (int i = 0; i < 4; ++i) {
            #pragma unroll
            for (int r = 0; r < 4; ++r) {
                const int row = m0 + wr + i * 16 + lq * 4 + r;
                float v = acc[i][j][r];
                if constexpr (EPI == 0) {
                    float z = v + bias[col];
                    Ch[(size_t)row * ldc + col] = (_Float16)tanh_fast(z);
                } else if constexpr (EPI == 1) {
                    Ch[(size_t)(col >> 9) * ((size_t)M_ * 512) + (size_t)row * 512 + (col & 511)] = (_Float16)v;
                } else {
                    Cf[(size_t)blockIdx.z * M_ * NOUT + (size_t)row * NOUT + col] = v;
                }
            }
        }
    }
}

// ---------------------------------------------------------------------------
// Split-K reduction + sigmoid epilogue for the final GEMM.
__global__ __launch_bounds__(256) void reduce_out(
    const float* __restrict__ Cp, const float* __restrict__ bias,
    const float* __restrict__ aux, float* __restrict__ out)
{
    const size_t i = (size_t)blockIdx.x * 256 + threadIdx.x;
    if (i >= (size_t)M_ * NOUT) return;
    const int row = (int)(i / NOUT);
    const int col = (int)(i % NOUT);
    float s = Cp[i] + Cp[i + (size_t)M_ * NOUT] + Cp[i + 2 * (size_t)M_ * NOUT];
    out[i] = sigmoid_fast(s + bias[col]) * aux[(size_t)row * FEAT + 257 + col];
}

// ---------------------------------------------------------------------------
// SRU scan reading SoA U planes + X directly via LDS double-buffer staging.
// repack_u is ELIMINATED. r3 lesson: direct 4-stream register prefetch needs
// 80 outstanding loads (> vmcnt 63) and collapses to latency-serial. Here each
// 40-step buffer is staged with exactly 20 global_load_lds (5 per plane x 4
// planes); double-buffered -> bounded outstanding; counted vmcnt(20) keeps the
// next buffer's loads in flight under the 40-step compute (~2400cy >> HBM lat).
// Single wave per block -> no barriers. Numerics identical to packed version.
__global__ __launch_bounds__(64) void sru_scan(
    const _Float16* __restrict__ U,   // 3 planes [M][512] (xt, fp, rp)
    const _Float16* __restrict__ X,   // [M][512] layer input
    _Float16* __restrict__ Xout,
    const float* __restrict__ v, const float* __restrict__ bg)
{
    __shared__ __align__(16) _Float16 lds[2][4][40][64];   // 40 KiB
    const int tid = threadIdx.x;
    const int b   = blockIdx.x >> 3;
    const int h0  = (blockIdx.x & 7) << 6;
    const int h   = h0 + tid;
    const float vf = v[h],       vr = v[512 + h];
    const float bf = bg[h],      br = bg[512 + h];

    const _Float16* plane0 = U;
    const _Float16* plane1 = U + (size_t)M_ * 512;
    const _Float16* plane2 = U + 2 * (size_t)M_ * 512;
    const _Float16* plane3 = X;

    const int lrow = tid >> 3;        // 0..7: t sub-row within a 1KB chunk
    const int lcol = (tid & 7) * 8;   // halves within row (16 B per lane)

    _Float16* ox = Xout + (size_t)b * T_ * 512 + h;

    // refill buffer bufi with t-rows [t0, t0+40)
    auto refill = [&](int bufi, int t0) {
        const size_t rbase = (size_t)(b * T_ + t0 + lrow) * 512 + h0 + lcol;
        #pragma unroll
        for (int j = 0; j < 5; ++j) {
            const size_t o = rbase + (size_t)(8 * j) * 512;
            gload16(plane0 + o, &lds[bufi][0][8 * j][0]);
            gload16(plane1 + o, &lds[bufi][1][8 * j][0]);
            gload16(plane2 + o, &lds[bufi][2][8 * j][0]);
            gload16(plane3 + o, &lds[bufi][3][8 * j][0]);
        }
    };

    refill(0, 0);
    float c = 0.f;
    int cur = 0;
    for (int tb = 0; tb < 25; ++tb) {
        const int t0 = tb * 40;
        if (tb + 1 < 25) {
            refill(cur ^ 1, t0 + 40);
            // 20 newest outstanding = next buffer; everything older (current
            // buffer's refill + prior stores) must drain.
            asm volatile("s_waitcnt vmcnt(20)" ::: "memory");
        } else {
            asm volatile("s_waitcnt vmcnt(0)" ::: "memory");
        }
        __builtin_amdgcn_sched_barrier(0);
        #pragma unroll
        for (int j = 0; j < 40; ++j) {
            const float xt = (float)lds[cur][0][j][tid];
            const float fp = (float)lds[cur][1][j][tid];
            const float rp = (float)lds[cur][2][j][tid];
            const float x  = (float)lds[cur][3][j][tid];
            const float f  = sigmoid_fast(fp + vf * c + bf);
            const float r  = sigmoid_fast(rp + vr * c + br);
            const float cn = f * c + (1.0f - f) * xt;
            const float hO = r * cn + (1.0f - r) * x;
            ox[(size_t)(t0 + j) * 512] = (_Float16)hO;
            c = cn;
        }
        cur ^= 1;
    }
}

// ---------------------------------------------------------------------------
// Fused conv6x6(asym pad 3,2) + maxpool3x3(pad 1) + bias + tanh.
// Packed fp16 via inline asm (v_pk_fma_f16 / v_pk_max_f16); alignbit windows;
// tanh AFTER pool (monotonic). Output k-major (k*512+h).
#define CVW 76   // cv row width (halves)

__global__ __launch_bounds__(320) void conv_pool(
    const _Float16* __restrict__ X, const unsigned int* __restrict__ ckp,
    const float* __restrict__ cb, _Float16* __restrict__ A3)
{
    __shared__ __align__(16) _Float16 in_s[23][80];       // fp16, rows padded to 80
    __shared__ __align__(16) _Float16 cv[9][18][CVW];     // raw conv fp16; -65504 = outside
    const int tid = threadIdx.x;
    int bi = blockIdx.x;
    const int th = bi & 7;  bi >>= 3;
    const int tt = bi % 63;
    const int b  = bi / 63;
    const int t0 = tt * 16, h0 = th * 64;

    for (int i = tid; i < 23 * 76; i += 320) {
        const int r = i / 76, cc = i % 76;
        const int gt = t0 - 4 + r, gh = h0 - 4 + cc;
        _Float16 val = (_Float16)0.f;   // conv zero-padding
        if (gt >= 0 && gt < T_ && gh >= 0 && gh < H_)
            val = X[((size_t)b * T_ + gt) * H_ + gh];
        in_s[r][cc] = val;
    }
    __syncthreads();

    // conv phase: 18 pt x 17 ph-groups = 306 tasks, one per thread
    if (tid < 306) {
        const int pt = tid / 17;        // conv row: ct = t0 - 1 + pt
        const int co = (tid % 17) * 4;  // conv col offset (co % 4 == 0)

        const int ct = t0 - 1 + pt;
        const bool rok = (ct >= 0) && (ct < T_);
        const int chb = h0 - 1 + co;
        const bool ok0 = rok && (chb + 0 >= 0) && (chb + 0 < H_);
        const bool ok1 = rok && (chb + 1 >= 0) && (chb + 1 < H_);
        const bool ok2 = rok && (chb + 2 >= 0) && (chb + 2 < H_);
        const bool ok3 = rok && (chb + 3 >= 0) && (chb + 3 < H_);

        unsigned acc0[9], acc1[9];      // packed (q0,q1) and (q2,q3), fp16 pairs
        #pragma unroll
        for (int k = 0; k < 9; ++k) { acc0[k] = 0u; acc1[k] = 0u; }

        #pragma unroll 1
        for (int ii = 0; ii < 6; ++ii) {
            const unsigned int* rw = (const unsigned int*)&in_s[pt + ii][co];  // 8-B aligned
            const uint2 a01 = *(const uint2*)(rw);
            const uint2 a23 = *(const uint2*)(rw + 2);
            const unsigned int A0 = a01.x, A1v = a01.y, A2 = a23.x, A3v = a23.y;
            const unsigned int A4 = rw[4];
            // misaligned pairs (1 instr each): M[i] = halves(co+2i+1, co+2i+2)
            const unsigned int M0 = __builtin_amdgcn_alignbit(A1v, A0, 16);
            const unsigned int M1 = __builtin_amdgcn_alignbit(A2, A1v, 16);
            const unsigned int M2 = __builtin_amdgcn_alignbit(A3v, A2, 16);
            const unsigned int M3 = __builtin_amdgcn_alignbit(A4, A3v, 16);

            const unsigned int* wt = ckp + ii * 6;   // + k*36 + J, wave-uniform (SGPR)
            #pragma unroll
            for (int k = 0; k < 9; ++k) {
                const unsigned int* wk = wt + k * 36;
                pk_fma_acc(acc0[k], wk[0], A0);   pk_fma_acc(acc1[k], wk[0], A1v);  // J=0
                pk_fma_acc(acc0[k], wk[1], M0);   pk_fma_acc(acc1[k], wk[1], M1);   // J=1
                pk_fma_acc(acc0[k], wk[2], A1v);  pk_fma_acc(acc1[k], wk[2], A2);   // J=2
                pk_fma_acc(acc0[k], wk[3], M1);   pk_fma_acc(acc1[k], wk[3], M2);   // J=3
                pk_fma_acc(acc0[k], wk[4], A2);   pk_fma_acc(acc1[k], wk[4], A3v);  // J=4
                pk_fma_acc(acc0[k], wk[5], M2);   pk_fma_acc(acc1[k], wk[5], M3);   // J=5
            }
        }

        const _Float16 NEG = (_Float16)(-65504.f);
        #pragma unroll
        for (int k = 0; k < 9; ++k) {
            const h2 pa = __builtin_bit_cast(h2, acc0[k]);
            const h2 pb = __builtin_bit_cast(h2, acc1[k]);
            half4 o;
            o[0] = ok0 ? pa[0] : NEG;
            o[1] = ok1 ? pa[1] : NEG;
            o[2] = ok2 ? pb[0] : NEG;
            o[3] = ok3 ? pb[1] : NEG;
            *(half4*)(&cv[k][pt][co]) = o;
        }
    }
    __syncthreads();

    // pool phase: 16 pt x 16 ph-groups of 4 = 256 tasks; packed fp16 max,
    // then bias+tanh in fp32 on the 4 pooled values only.
    if (tid < 256) {
        const int pt = tid >> 4;
        const int gt = t0 + pt;
        if (gt < T_) {
            const int ph = (tid & 15) * 4;
            _Float16* dst = A3 + ((size_t)b * T_ + gt) * KHID + (h0 + ph);
            #pragma unroll
            for (int k = 0; k < 9; ++k) {
                unsigned q01 = 0xFC00FC00u, q23 = 0xFC00FC00u;   // (-inf,-inf) fp16
                #pragma unroll
                for (int dr = 0; dr < 3; ++dr) {
                    const unsigned* cr = (const unsigned*)&cv[k][pt + dr][ph];
                    const uint2 w01 = *(const uint2*)(cr);     // (v0,v1),(v2,v3)
                    const unsigned w2 = cr[2];                 // (v4,v5)
                    const unsigned m12 = __builtin_amdgcn_alignbit(w01.y, w01.x, 16); // (v1,v2)
                    const unsigned m34 = __builtin_amdgcn_alignbit(w2, w01.y, 16);    // (v3,v4)
                    q01 = pk_max(q01, pk_max(pk_max(w01.x, m12), w01.y));
                    q23 = pk_max(q23, pk_max(pk_max(w01.y, m34), w2));
                }
                const h2 qa = __builtin_bit_cast(h2, q01);
                const h2 qb = __builtin_bit_cast(h2, q23);
                const float bk = cb[k];
                half4 o;
                o[0] = (_Float16)tanh_fast((float)qa[0] + bk);
                o[1] = (_Float16)tanh_fast((float)qa[1] + bk);
                o[2] = (_Float16)tanh_fast((float)qb[0] + bk);
                o[3] = (_Float16)tanh_fast((float)qb[1] + bk);
                *(half4*)(dst + (size_t)k * 512) = o;
            }
        }
    }
}

// ---------------------------------------------------------------------------
extern "C" void kernel_launch(void* const* d_in, const int* in_sizes, int n_in,
                              void* d_out, int out_size, void* d_ws, size_t ws_size,
                              hipStream_t stream) {
    const float* inputs = (const float*)d_in[0];
    const float* W_in   = (const float*)d_in[1];
    const float* b_in   = (const float*)d_in[2];
    const float* W_rnn  = (const float*)d_in[3];
    const float* v_rnn  = (const float*)d_in[4];
    const float* b_rnn  = (const float*)d_in[5];
    const float* conv_k = (const float*)d_in[6];
    const float* conv_b = (const float*)d_in[7];
    const float* W_out  = (const float*)d_in[8];
    const float* b_out  = (const float*)d_in[9];
    float* out = (float*)d_out;

    char* ws = (char*)d_ws;
    size_t off = 0;
    auto take = [&](size_t bytes) -> char* {
        off = (off + 255) & ~(size_t)255;
        char* p = ws + off;
        off += bytes;
        return p;
    };
    // W3T first so it survives; A1..X1 form a dead span at G3 time for Cp alias.
    _Float16* W3T  = (_Float16*)take((size_t)NOUT * KHID * 2);  // W_out[:,257:514)^T, K-permuted
    _Float16* A1   = (_Float16*)take((size_t)M_ * FEATP * 2);   // inputs fp16, padded (dead after G1)
    _Float16* W1T  = (_Float16*)take((size_t)H_ * FEATP * 2);   // W_in^T
    _Float16* W2T0 = (_Float16*)take((size_t)H3 * H_ * 2);      // W_rnn[0]^T
    _Float16* W2T1 = (_Float16*)take((size_t)H3 * H_ * 2);      // W_rnn[1]^T
    _Float16* X0   = (_Float16*)take((size_t)M_ * H_ * 2);      // tanh(G1); scan1 output (X2)
    _Float16* X1   = (_Float16*)take((size_t)M_ * H_ * 2);      // scan0 output
    _Float16* U    = (_Float16*)take(3 * (size_t)M_ * 512 * 2); // SoA U planes (xt,fp,rp)
    _Float16* A3   = (_Float16*)take((size_t)M_ * KHID * 2);    // pooled conv, k-major (k*512+h)
    unsigned int* ckp = (unsigned int*)take(9 * 36 * 4);        // packed dup'd fp16 conv weights
    // Split-K partials alias the dead A1..X1 span (49.4 MB < 62.4 MB span):
    float* Cp = (float*)A1;
    _Float16* X2 = X0;  // X0 dead after G2-layer0+scan0 -> reuse for scan1 output

    // --- weight/input preprocessing (fp32 -> fp16, transpose to NxK) ---
    {
        size_t n = (size_t)M_ * FEATP;
        convert_inputs<<<dim3((unsigned)((n + 255) / 256)), 256, 0, stream>>>(inputs, A1);
    }
    pack_ck<<<dim3(1), 384, 0, stream>>>(conv_k, ckp);
    transpose_w<<<dim3(25, 16), 256, 0, stream>>>(W_in, W1T, FEAT, H_, H_, 0, FEATP, 0);
    transpose_w<<<dim3(16, 48), 256, 0, stream>>>(W_rnn, W2T0, H_, H3, H3, 0, H_, 0);
    transpose_w<<<dim3(16, 48), 256, 0, stream>>>(W_rnn + (size_t)H_ * H3, W2T1, H_, H3, H3, 0, H_, 0);
    transpose_w<<<dim3(144, 9), 256, 0, stream>>>(W_out, W3T, KHID, NOUT, FEAT, 257, KHID, 1);

    // --- G1: X0 = tanh(inputs @ W_in + b_in) ---
    gemm_kernel<0><<<dim3(125, 4), 256, 0, stream>>>(A1, W1T, FEATP, 25, H_, X0, nullptr, H_, b_in);

    // --- SRU layer 0: U-GEMM (SoA) -> LDS-staged scan (reads planes directly) ---
    gemm_kernel<1><<<dim3(125, 12), 256, 0, stream>>>(X0, W2T0, H_, 16, H3, U, nullptr, 0, nullptr);
    sru_scan<<<dim3(128), 64, 0, stream>>>(U, X0, X1, v_rnn, b_rnn);

    // --- SRU layer 1 ---
    gemm_kernel<1><<<dim3(125, 12), 256, 0, stream>>>(X1, W2T1, H_, 16, H3, U, nullptr, 0, nullptr);
    sru_scan<<<dim3(128), 64, 0, stream>>>(U, X1, X2, v_rnn + 1024, b_rnn + 1024);

    // --- conv + maxpool + bias + tanh fused, producing final-GEMM A matrix ---
    conv_pool<<<dim3(16 * 63 * 8), 320, 0, stream>>>(X2, ckp, conv_b, A3);

    // --- G3 split-K: Cp[z] = A3 @ W3T (K-slice z), then reduce+sigmoid+mask ---
    gemm_kernel<3><<<dim3(125, 3, KSLICES), 256, 0, stream>>>(A3, W3T, KHID, 144 / KSLICES, NOUT, nullptr, Cp, 0, nullptr);
    {
        const unsigned nred = (unsigned)(((size_t)M_ * NOUT + 255) / 256);
        reduce_out<<<dim3(nred), 256, 0, stream>>>(Cp, b_out + 257, inputs, out);
    }
}

// Round 8
// 697.455 us; speedup vs baseline: 2.1298x; 1.0424x over previous
//
#include <hip/hip_runtime.h>
#include <hip/hip_bf16.h>

// Problem constants
#define B_    16
#define T_    1000
#define FEAT  771
#define FEATP 800      // 771 padded to 25*32 (exact BK multiple -> guard-free GEMM)
#define H_    512
#define H3    1536
#define KN_   9
#define KHID  4608     // H*KN
#define M_    16000    // B*T
#define NOUT  257      // output column slice [257:514)
#define KSLICES 2      // split-K factor for the final GEMM

typedef _Float16 half8 __attribute__((ext_vector_type(8)));
typedef _Float16 half4 __attribute__((ext_vector_type(4)));
typedef _Float16 half2v __attribute__((ext_vector_type(2)));
typedef _Float16 h2 __attribute__((ext_vector_type(2)));
typedef float    floatx4 __attribute__((ext_vector_type(4)));

// tanh(z) = 1 - 2/(1+e^{2z})  — saturates correctly at +/-inf, no NaN
__device__ inline float tanh_fast(float z) {
    return 1.0f - 2.0f / (1.0f + __expf(2.0f * z));
}
__device__ inline float sigmoid_fast(float z) {
    return 1.0f / (1.0f + __expf(-z));
}

// async global->LDS, 16B per lane; LDS dst must be wave-uniform base
__device__ inline void gload16(const _Float16* g, _Float16* l) {
    __builtin_amdgcn_global_load_lds(
        (const __attribute__((address_space(1))) void*)g,
        (__attribute__((address_space(3))) void*)l, 16, 0, 0);
}

// Guaranteed packed fp16 ops; w is wave-uniform (SGPR src0).
__device__ inline void pk_fma_acc(unsigned& acc, unsigned w, unsigned x) {
    asm("v_pk_fma_f16 %0, %1, %2, %0" : "+v"(acc) : "s"(w), "v"(x));
}
__device__ inline unsigned pk_max(unsigned a, unsigned b) {
    unsigned d;
    asm("v_pk_max_f16 %0, %1, %2" : "=v"(d) : "v"(a), "v"(b));
    return d;
}

// ---------------------------------------------------------------------------
// fp32 -> fp16 convert of inputs, padding rows 771 -> 800 with zeros.
// Block 0 additionally packs ALL 324 conv weights (stride loop — r7 bug was
// threadIdx.x < 324 with only 256 threads, leaving kernels 7-8 garbage).
__global__ void convert_inputs(const float* __restrict__ in, _Float16* __restrict__ A1,
                               const float* __restrict__ ck, unsigned int* __restrict__ ckp) {
    if (blockIdx.x == 0) {
        for (int j = threadIdx.x; j < 9 * 36; j += 256) {
            const _Float16 w = (_Float16)ck[j];
            const unsigned short u = __builtin_bit_cast(unsigned short, w);
            ckp[j] = ((unsigned int)u << 16) | u;
        }
    }
    size_t i = (size_t)blockIdx.x * 256 + threadIdx.x;
    if (i >= (size_t)M_ * FEATP) return;
    size_t r = i / FEATP;
    int   cc = (int)(i % FEATP);
    A1[i] = (cc < FEAT) ? (_Float16)in[r * FEAT + cc] : (_Float16)0.f;
}

// ---------------------------------------------------------------------------
// LDS-tiled transpose+convert: Wt[n*Kp + kidx] = (k<K) ? W[k*ldw + coloff + n] : 0
// perm9: kidx = (k%9)*512 + k/9  (k-major planes for the conv output layout)
// blockIdx.z strides src by zsrc and dst by zdst (batched transposes).
__global__ __launch_bounds__(256) void transpose_w(
    const float* __restrict__ W, _Float16* __restrict__ Wt,
    int K, int N, int ldw, int coloff, int Kp, int perm9,
    size_t zsrc, size_t zdst)
{
    W  += (size_t)blockIdx.z * zsrc;
    Wt += (size_t)blockIdx.z * zdst;
    __shared__ float tile[32][33];
    const int kb = blockIdx.x * 32;
    const int nb = blockIdx.y * 32;
    const int tx = threadIdx.x & 31;
    const int ty = threadIdx.x >> 5;   // 0..7
    #pragma unroll
    for (int r = ty; r < 32; r += 8) {
        const int k = kb + r, n = nb + tx;
        tile[r][tx] = (k < K && n < N) ? W[(size_t)k * ldw + coloff + n] : 0.f;
    }
    __syncthreads();
    #pragma unroll
    for (int r = ty; r < 32; r += 8) {
        const int n = nb + r, k = kb + tx;
        if (n < N && k < Kp) {
            size_t kidx = (size_t)k;
            if (perm9) kidx = (size_t)(k % 9) * 512 + (size_t)(k / 9);
            Wt[(size_t)n * Kp + kidx] = (_Float16)tile[tx][r];
        }
    }
}

// ---------------------------------------------------------------------------
// Tiled fp16 MFMA GEMM: C[M x N] = A[M x Kp] * Bt[N x Kp]^T, fp32 accumulate.
// 128x128 block tile, BK=32, 4 waves (2x2), each wave 4x4 of 16x16x32 MFMA.
// 2-phase prefetch: double-buffered LDS, tile k+1 staged via global_load_lds
// BEFORE computing tile k; one vmcnt(0)+raw-barrier per K-step.
// RAG=1: ragged-N — wave-uniform guards skip B-frag loads + MFMAs for
// fragment columns >= Nb (G3's last n-tile: 1/128 cols live -> -29% MFMA).
template <int EPI, int RAG>
__global__ __launch_bounds__(256) void gemm_kernel(
    const _Float16* __restrict__ A, const _Float16* __restrict__ Bt,
    int Kp, int nk, int Nb,
    _Float16* __restrict__ Ch, float* __restrict__ Cf, int ldc,
    const float* __restrict__ bias)
{
    __shared__ __align__(16) _Float16 As[2][128][32];
    __shared__ __align__(16) _Float16 Bs[2][128][32];

    const int tid  = threadIdx.x;
    const int m0   = blockIdx.x * 128;
    const int n0   = blockIdx.y * 128;
    const int koff = blockIdx.z * (nk << 5);   // K-slice origin
    const int wave = tid >> 6;
    const int lane = tid & 63;
    const int wr   = (wave >> 1) << 6;   // wave row offset (0/64)
    const int wc   = (wave & 1) << 6;    // wave col offset (0/64)
    const int lrow = lane & 15;
    const int lq   = lane >> 4;          // 0..3
    const bool waveAlive = !RAG || (n0 + wc < Nb);

    // staging: wave w stages rows [w*32, w*32+32), 2 instrs per matrix
    const int srow0  = wave * 32 + (lane >> 2);   // rows for instr 0
    const int schunk = (lane & 3) * 8;            // halves within row
    const _Float16* aSrc = A  + (size_t)(m0 + srow0) * Kp + koff + schunk;
    const _Float16* bSrc = Bt + (size_t)(n0 + srow0) * Kp + koff + schunk;
    const size_t rstep = (size_t)16 * Kp;

    floatx4 acc[4][4];
    #pragma unroll
    for (int i = 0; i < 4; ++i)
        #pragma unroll
        for (int j = 0; j < 4; ++j)
            #pragma unroll
            for (int r = 0; r < 4; ++r) acc[i][j][r] = 0.f;

    // prologue: stage tile 0 into buffer 0
    gload16(aSrc,         &As[0][wave * 32][0]);
    gload16(aSrc + rstep, &As[0][wave * 32 + 16][0]);
    gload16(bSrc,         &Bs[0][wave * 32][0]);
    gload16(bSrc + rstep, &Bs[0][wave * 32 + 16][0]);
    asm volatile("s_waitcnt vmcnt(0)" ::: "memory");
    __builtin_amdgcn_s_barrier();

    for (int kc = 0; kc < nk; ++kc) {
        const int cur = kc & 1;
        if (kc + 1 < nk) {   // prefetch next tile into the other buffer
            const _Float16* a2 = aSrc + (size_t)(kc + 1) * 32;
            const _Float16* b2 = bSrc + (size_t)(kc + 1) * 32;
            gload16(a2,         &As[cur ^ 1][wave * 32][0]);
            gload16(a2 + rstep, &As[cur ^ 1][wave * 32 + 16][0]);
            gload16(b2,         &Bs[cur ^ 1][wave * 32][0]);
            gload16(b2 + rstep, &Bs[cur ^ 1][wave * 32 + 16][0]);
        }

        if (waveAlive) {
            half8 af[4], bfr[4];
            #pragma unroll
            for (int i = 0; i < 4; ++i) af[i] = *(const half8*)(&As[cur][wr + i * 16 + lrow][lq * 8]);
            #pragma unroll
            for (int j = 0; j < 4; ++j) {
                if (RAG && n0 + wc + j * 16 >= Nb) continue;
                bfr[j] = *(const half8*)(&Bs[cur][wc + j * 16 + lrow][lq * 8]);
            }
            #pragma unroll
            for (int i = 0; i < 4; ++i)
                #pragma unroll
                for (int j = 0; j < 4; ++j) {
                    if (RAG && n0 + wc + j * 16 >= Nb) continue;
                    acc[i][j] = __builtin_amdgcn_mfma_f32_16x16x32_f16(af[i], bfr[j], acc[i][j], 0, 0, 0);
                }
        }

        if (kc + 1 < nk) {
            asm volatile("s_waitcnt vmcnt(0)" ::: "memory");
            __builtin_amdgcn_s_barrier();
        }
    }

    // Epilogue: C/D layout col=lane&15, row=quad*4+reg
    #pragma unroll
    for (int j = 0; j < 4; ++j) {
        const int col = n0 + wc + j * 16 + lrow;
        if (col >= Nb) continue;
        #pragma unroll
        for (int i = 0; i < 4; ++i) {
            #pragma unroll
            for (int r = 0; r < 4; ++r) {
                const int row = m0 + wr + i * 16 + lq * 4 + r;
                float v = acc[i][j][r];
                if constexpr (EPI == 0) {
                    float z = v + bias[col];
                    Ch[(size_t)row * ldc + col] = (_Float16)tanh_fast(z);
                } else if constexpr (EPI == 1) {
                    Ch[(size_t)(col >> 9) * ((size_t)M_ * 512) + (size_t)row * 512 + (col & 511)] = (_Float16)v;
                } else {
                    Cf[(size_t)blockIdx.z * M_ * NOUT + (size_t)row * NOUT + col] = v;
                }
            }
        }
    }
}

// ---------------------------------------------------------------------------
// Split-K reduction + sigmoid epilogue for the final GEMM (KSLICES=2).
__global__ __launch_bounds__(256) void reduce_out(
    const float* __restrict__ Cp, const float* __restrict__ bias,
    const float* __restrict__ aux, float* __restrict__ out)
{
    const size_t i = (size_t)blockIdx.x * 256 + threadIdx.x;
    if (i >= (size_t)M_ * NOUT) return;
    const int row = (int)(i / NOUT);
    const int col = (int)(i % NOUT);
    float s = Cp[i] + Cp[i + (size_t)M_ * NOUT];
    out[i] = sigmoid_fast(s + bias[col]) * aux[(size_t)row * FEAT + 257 + col];
}

// ---------------------------------------------------------------------------
// SRU scan reading SoA U planes + X directly via LDS double-buffer staging.
// Each 40-step buffer staged with exactly 20 global_load_lds; double-buffered;
// counted vmcnt(20) keeps next buffer's loads in flight under the compute.
__global__ __launch_bounds__(64) void sru_scan(
    const _Float16* __restrict__ U,   // 3 planes [M][512] (xt, fp, rp)
    const _Float16* __restrict__ X,   // [M][512] layer input
    _Float16* __restrict__ Xout,
    const float* __restrict__ v, const float* __restrict__ bg)
{
    __shared__ __align__(16) _Float16 lds[2][4][40][64];   // 40 KiB
    const int tid = threadIdx.x;
    const int b   = blockIdx.x >> 3;
    const int h0  = (blockIdx.x & 7) << 6;
    const int h   = h0 + tid;
    const float vf = v[h],       vr = v[512 + h];
    const float bf = bg[h],      br = bg[512 + h];

    const _Float16* plane0 = U;
    const _Float16* plane1 = U + (size_t)M_ * 512;
    const _Float16* plane2 = U + 2 * (size_t)M_ * 512;
    const _Float16* plane3 = X;

    const int lrow = tid >> 3;        // 0..7: t sub-row within a 1KB chunk
    const int lcol = (tid & 7) * 8;   // halves within row (16 B per lane)

    _Float16* ox = Xout + (size_t)b * T_ * 512 + h;

    // refill buffer bufi with t-rows [t0, t0+40)
    auto refill = [&](int bufi, int t0) {
        const size_t rbase = (size_t)(b * T_ + t0 + lrow) * 512 + h0 + lcol;
        #pragma unroll
        for (int j = 0; j < 5; ++j) {
            const size_t o = rbase + (size_t)(8 * j) * 512;
            gload16(plane0 + o, &lds[bufi][0][8 * j][0]);
            gload16(plane1 + o, &lds[bufi][1][8 * j][0]);
            gload16(plane2 + o, &lds[bufi][2][8 * j][0]);
            gload16(plane3 + o, &lds[bufi][3][8 * j][0]);
        }
    };

    refill(0, 0);
    float c = 0.f;
    int cur = 0;
    for (int tb = 0; tb < 25; ++tb) {
        const int t0 = tb * 40;
        if (tb + 1 < 25) {
            refill(cur ^ 1, t0 + 40);
            asm volatile("s_waitcnt vmcnt(20)" ::: "memory");
        } else {
            asm volatile("s_waitcnt vmcnt(0)" ::: "memory");
        }
        __builtin_amdgcn_sched_barrier(0);
        #pragma unroll
        for (int j = 0; j < 40; ++j) {
            const float xt = (float)lds[cur][0][j][tid];
            const float fp = (float)lds[cur][1][j][tid];
            const float rp = (float)lds[cur][2][j][tid];
            const float x  = (float)lds[cur][3][j][tid];
            const float f  = sigmoid_fast(fp + vf * c + bf);
            const float r  = sigmoid_fast(rp + vr * c + br);
            const float cn = f * c + (1.0f - f) * xt;
            const float hO = r * cn + (1.0f - r) * x;
            ox[(size_t)(t0 + j) * 512] = (_Float16)hO;
            c = cn;
        }
        cur ^= 1;
    }
}

// ---------------------------------------------------------------------------
// Fused conv6x6(asym pad 3,2) + maxpool3x3(pad 1) + bias + tanh.
// Packed fp16 via inline asm; pool is VERTICAL-FIRST (element-wise pk_max over
// the 3 rows, then one horizontal pass): 12 VALU/k vs 24, identical result by
// max-associativity. tanh AFTER pool (monotonic). Output k-major (k*512+h).
#define CVW 76   // cv row width (halves)

__global__ __launch_bounds__(320) void conv_pool(
    const _Float16* __restrict__ X, const unsigned int* __restrict__ ckp,
    const float* __restrict__ cb, _Float16* __restrict__ A3)
{
    __shared__ __align__(16) _Float16 in_s[23][80];       // fp16, rows padded to 80
    __shared__ __align__(16) _Float16 cv[9][18][CVW];     // raw conv fp16; -65504 = outside
    const int tid = threadIdx.x;
    int bi = blockIdx.x;
    const int th = bi & 7;  bi >>= 3;
    const int tt = bi % 63;
    const int b  = bi / 63;
    const int t0 = tt * 16, h0 = th * 64;

    for (int i = tid; i < 23 * 76; i += 320) {
        const int r = i / 76, cc = i % 76;
        const int gt = t0 - 4 + r, gh = h0 - 4 + cc;
        _Float16 val = (_Float16)0.f;   // conv zero-padding
        if (gt >= 0 && gt < T_ && gh >= 0 && gh < H_)
            val = X[((size_t)b * T_ + gt) * H_ + gh];
        in_s[r][cc] = val;
    }
    __syncthreads();

    // conv phase: 18 pt x 17 ph-groups = 306 tasks, one per thread
    if (tid < 306) {
        const int pt = tid / 17;        // conv row: ct = t0 - 1 + pt
        const int co = (tid % 17) * 4;  // conv col offset (co % 4 == 0)

        const int ct = t0 - 1 + pt;
        const bool rok = (ct >= 0) && (ct < T_);
        const int chb = h0 - 1 + co;
        const bool ok0 = rok && (chb + 0 >= 0) && (chb + 0 < H_);
        const bool ok1 = rok && (chb + 1 >= 0) && (chb + 1 < H_);
        const bool ok2 = rok && (chb + 2 >= 0) && (chb + 2 < H_);
        const bool ok3 = rok && (chb + 3 >= 0) && (chb + 3 < H_);

        unsigned acc0[9], acc1[9];      // packed (q0,q1) and (q2,q3), fp16 pairs
        #pragma unroll
        for (int k = 0; k < 9; ++k) { acc0[k] = 0u; acc1[k] = 0u; }

        #pragma unroll 1
        for (int ii = 0; ii < 6; ++ii) {
            const unsigned int* rw = (const unsigned int*)&in_s[pt + ii][co];  // 8-B aligned
            const uint2 a01 = *(const uint2*)(rw);
            const uint2 a23 = *(const uint2*)(rw + 2);
            const unsigned int A0 = a01.x, A1v = a01.y, A2 = a23.x, A3v = a23.y;
            const unsigned int A4 = rw[4];
            // misaligned pairs (1 instr each): M[i] = halves(co+2i+1, co+2i+2)
            const unsigned int M0 = __builtin_amdgcn_alignbit(A1v, A0, 16);
            const unsigned int M1 = __builtin_amdgcn_alignbit(A2, A1v, 16);
            const unsigned int M2 = __builtin_amdgcn_alignbit(A3v, A2, 16);
            const unsigned int M3 = __builtin_amdgcn_alignbit(A4, A3v, 16);

            const unsigned int* wt = ckp + ii * 6;   // + k*36 + J, wave-uniform (SGPR)
            #pragma unroll
            for (int k = 0; k < 9; ++k) {
                const unsigned int* wk = wt + k * 36;
                pk_fma_acc(acc0[k], wk[0], A0);   pk_fma_acc(acc1[k], wk[0], A1v);  // J=0
                pk_fma_acc(acc0[k], wk[1], M0);   pk_fma_acc(acc1[k], wk[1], M1);   // J=1
                pk_fma_acc(acc0[k], wk[2], A1v);  pk_fma_acc(acc1[k], wk[2], A2);   // J=2
                pk_fma_acc(acc0[k], wk[3], M1);   pk_fma_acc(acc1[k], wk[3], M2);   // J=3
                pk_fma_acc(acc0[k], wk[4], A2);   pk_fma_acc(acc1[k], wk[4], A3v);  // J=4
                pk_fma_acc(acc0[k], wk[5], M2);   pk_fma_acc(acc1[k], wk[5], M3);   // J=5
            }
        }

        const _Float16 NEG = (_Float16)(-65504.f);
        #pragma unroll
        for (int k = 0; k < 9; ++k) {
            const h2 pa = __builtin_bit_cast(h2, acc0[k]);
            const h2 pb = __builtin_bit_cast(h2, acc1[k]);
            half4 o;
            o[0] = ok0 ? pa[0] : NEG;
            o[1] = ok1 ? pa[1] : NEG;
            o[2] = ok2 ? pb[0] : NEG;
            o[3] = ok3 ? pb[1] : NEG;
            *(half4*)(&cv[k][pt][co]) = o;
        }
    }
    __syncthreads();

    // pool phase: 16 pt x 16 ph-groups of 4 = 256 tasks; vertical-first packed
    // max, then horizontal; bias+tanh in fp32 on the 4 pooled values only.
    if (tid < 256) {
        const int pt = tid >> 4;
        const int gt = t0 + pt;
        if (gt < T_) {
            const int ph = (tid & 15) * 4;
            _Float16* dst = A3 + ((size_t)b * T_ + gt) * KHID + (h0 + ph);
            #pragma unroll
            for (int k = 0; k < 9; ++k) {
                const unsigned* c0 = (const unsigned*)&cv[k][pt + 0][ph];
                const unsigned* c1 = (const unsigned*)&cv[k][pt + 1][ph];
                const unsigned* c2 = (const unsigned*)&cv[k][pt + 2][ph];
                const uint2 x0 = *(const uint2*)c0;  const unsigned y0 = c0[2];
                const uint2 x1 = *(const uint2*)c1;  const unsigned y1 = c1[2];
                const uint2 x2 = *(const uint2*)c2;  const unsigned y2 = c2[2];
                // vertical max (element-wise over 3 rows)
                const unsigned VA = pk_max(pk_max(x0.x, x1.x), x2.x);  // (u0,u1)
                const unsigned VB = pk_max(pk_max(x0.y, x1.y), x2.y);  // (u2,u3)
                const unsigned VC = pk_max(pk_max(y0,   y1),   y2);    // (u4,u5)
                // horizontal 3-window max on the vertical result
                const unsigned m12 = __builtin_amdgcn_alignbit(VB, VA, 16);  // (u1,u2)
                const unsigned m34 = __builtin_amdgcn_alignbit(VC, VB, 16);  // (u3,u4)
                const unsigned q01 = pk_max(pk_max(VA, m12), VB);
                const unsigned q23 = pk_max(pk_max(VB, m34), VC);
                const h2 qa = __builtin_bit_cast(h2, q01);
                const h2 qb = __builtin_bit_cast(h2, q23);
                const float bk = cb[k];
                half4 o;
                o[0] = (_Float16)tanh_fast((float)qa[0] + bk);
                o[1] = (_Float16)tanh_fast((float)qa[1] + bk);
                o[2] = (_Float16)tanh_fast((float)qb[0] + bk);
                o[3] = (_Float16)tanh_fast((float)qb[1] + bk);
                *(half4*)(dst + (size_t)k * 512) = o;
            }
        }
    }
}

// ---------------------------------------------------------------------------
extern "C" void kernel_launch(void* const* d_in, const int* in_sizes, int n_in,
                              void* d_out, int out_size, void* d_ws, size_t ws_size,
                              hipStream_t stream) {
    const float* inputs = (const float*)d_in[0];
    const float* W_in   = (const float*)d_in[1];
    const float* b_in   = (const float*)d_in[2];
    const float* W_rnn  = (const float*)d_in[3];
    const float* v_rnn  = (const float*)d_in[4];
    const float* b_rnn  = (const float*)d_in[5];
    const float* conv_k = (const float*)d_in[6];
    const float* conv_b = (const float*)d_in[7];
    const float* W_out  = (const float*)d_in[8];
    const float* b_out  = (const float*)d_in[9];
    float* out = (float*)d_out;

    char* ws = (char*)d_ws;
    size_t off = 0;
    auto take = [&](size_t bytes) -> char* {
        off = (off + 255) & ~(size_t)255;
        char* p = ws + off;
        off += bytes;
        return p;
    };
    // W3T first so it survives; A1..X1 form a dead span at G3 time for Cp alias.
    _Float16* W3T  = (_Float16*)take((size_t)NOUT * KHID * 2);  // W_out[:,257:514)^T, K-permuted
    _Float16* A1   = (_Float16*)take((size_t)M_ * FEATP * 2);   // inputs fp16, padded (dead after G1)
    _Float16* W1T  = (_Float16*)take((size_t)H_ * FEATP * 2);   // W_in^T
    _Float16* W2T0 = (_Float16*)take((size_t)H3 * H_ * 2);      // W_rnn[0]^T
    _Float16* W2T1 = (_Float16*)take((size_t)H3 * H_ * 2);      // W_rnn[1]^T (contiguous after W2T0)
    _Float16* X0   = (_Float16*)take((size_t)M_ * H_ * 2);      // tanh(G1); scan1 output (X2)
    _Float16* X1   = (_Float16*)take((size_t)M_ * H_ * 2);      // scan0 output
    _Float16* U    = (_Float16*)take(3 * (size_t)M_ * 512 * 2); // SoA U planes (xt,fp,rp)
    _Float16* A3   = (_Float16*)take((size_t)M_ * KHID * 2);    // pooled conv, k-major (k*512+h)
    unsigned int* ckp = (unsigned int*)take(9 * 36 * 4);        // packed dup'd fp16 conv weights
    // Split-K partials alias the dead A1..X1 span (32.9 MB < 62.4 MB span):
    float* Cp = (float*)A1;
    _Float16* X2 = X0;  // X0 dead after G2-layer0+scan0 -> reuse for scan1 output

    // --- weight/input preprocessing (fp32 -> fp16, transpose to NxK) ---
    {
        size_t n = (size_t)M_ * FEATP;
        convert_inputs<<<dim3((unsigned)((n + 255) / 256)), 256, 0, stream>>>(inputs, A1, conv_k, ckp);
    }
    transpose_w<<<dim3(25, 16), 256, 0, stream>>>(W_in, W1T, FEAT, H_, H_, 0, FEATP, 0, 0, 0);
    transpose_w<<<dim3(16, 48, 2), 256, 0, stream>>>(W_rnn, W2T0, H_, H3, H3, 0, H_, 0,
                                                     (size_t)H_ * H3, (size_t)H3 * H_);
    transpose_w<<<dim3(144, 9), 256, 0, stream>>>(W_out, W3T, KHID, NOUT, FEAT, 257, KHID, 1, 0, 0);

    // --- G1: X0 = tanh(inputs @ W_in + b_in) ---
    gemm_kernel<0, 0><<<dim3(125, 4), 256, 0, stream>>>(A1, W1T, FEATP, 25, H_, X0, nullptr, H_, b_in);

    // --- SRU layer 0: U-GEMM (SoA) -> LDS-staged scan (reads planes directly) ---
    gemm_kernel<1, 0><<<dim3(125, 12), 256, 0, stream>>>(X0, W2T0, H_, 16, H3, U, nullptr, 0, nullptr);
    sru_scan<<<dim3(128), 64, 0, stream>>>(U, X0, X1, v_rnn, b_rnn);

    // --- SRU layer 1 ---
    gemm_kernel<1, 0><<<dim3(125, 12), 256, 0, stream>>>(X1, W2T1, H_, 16, H3, U, nullptr, 0, nullptr);
    sru_scan<<<dim3(128), 64, 0, stream>>>(U, X1, X2, v_rnn + 1024, b_rnn + 1024);

    // --- conv + maxpool + bias + tanh fused, producing final-GEMM A matrix ---
    conv_pool<<<dim3(16 * 63 * 8), 320, 0, stream>>>(X2, ckp, conv_b, A3);

    // --- G3 split-K (ragged-N): Cp[z] = A3 @ W3T, then reduce+sigmoid+mask ---
    gemm_kernel<3, 1><<<dim3(125, 3, KSLICES), 256, 0, stream>>>(A3, W3T, KHID, 144 / KSLICES, NOUT, nullptr, Cp, 0, nullptr);
    {
        const unsigned nred = (unsigned)(((size_t)M_ * NOUT + 255) / 256);
        reduce_out<<<dim3(nred), 256, 0, stream>>>(Cp, b_out + 257, inputs, out);
    }
}